// Round 7
// baseline (393.489 us; speedup 1.0000x reference)
//
#include <hip/hip_runtime.h>
#include <math.h>

#define S_LEN 2048
#define BATCH 2
#define EMB 768
#define NH 8
#define HD 96
#define NTOK (BATCH*S_LEN)
#define RSQRT_D 0.10206207261596575f   // 1/sqrt(96)

typedef unsigned short u16;
typedef __attribute__((ext_vector_type(8))) short bf16x8;
typedef __attribute__((ext_vector_type(4))) float f32x4;

#define MFMA16(a,b,c) __builtin_amdgcn_mfma_f32_16x16x32_bf16(a,b,c,0,0,0)

__device__ __forceinline__ u16 f2bf(float f){
    unsigned u = __float_as_uint(f);
    return (u16)((u + 0x7fffu + ((u>>16)&1u)) >> 16);
}
__device__ __forceinline__ float bf2f(unsigned u){
    return __uint_as_float(u << 16);
}

union U16x8 { u16 u[8]; float4 f4; };
union U16x4 { u16 u[4]; uint2 v2; };

// ---------------------------------------------------------------------------
// f32 -> bf16 elementwise convert (vectorized x4)
// ---------------------------------------------------------------------------
__global__ __launch_bounds__(256) void cvt_bf16_kernel(
    const float* __restrict__ src, u16* __restrict__ dst, int n4)
{
    int i = blockIdx.x * 256 + threadIdx.x;
    if (i < n4) {
        float4 v = ((const float4*)src)[i];
        U16x4 o;
        o.u[0] = f2bf(v.x); o.u[1] = f2bf(v.y); o.u[2] = f2bf(v.z); o.u[3] = f2bf(v.w);
        *(uint2*)(dst + (size_t)i*4) = o.v2;
    }
}

// ---------------------------------------------------------------------------
// W[768][768] f32 -> Wt[n][k] bf16 (transpose + convert). grid (12,12), 256thr
// ---------------------------------------------------------------------------
__global__ __launch_bounds__(256) void transcvt_kernel(
    const float* __restrict__ W, u16* __restrict__ Wt)
{
    __shared__ float T[64][65];
    const int t = threadIdx.x;
    const int k0 = blockIdx.y * 64, n0 = blockIdx.x * 64;
    #pragma unroll
    for (int i = 0; i < 4; ++i) {
        int idx = t + 256*i;
        int r = idx >> 4, c4 = idx & 15;
        float4 v = *(const float4*)(W + (size_t)(k0 + r)*EMB + n0 + c4*4);
        T[r][c4*4+0] = v.x; T[r][c4*4+1] = v.y; T[r][c4*4+2] = v.z; T[r][c4*4+3] = v.w;
    }
    __syncthreads();
    #pragma unroll
    for (int i = 0; i < 2; ++i) {
        int idx = t + 256*i;
        int n = idx >> 3, c = idx & 7;
        U16x8 o;
        #pragma unroll
        for (int e = 0; e < 8; ++e) o.u[e] = f2bf(T[c*8+e][n]);
        *(float4*)(Wt + (size_t)(n0 + n)*EMB + k0 + c*8) = o.f4;
    }
}

// ---------------------------------------------------------------------------
// QKV projection MFMA (unchanged)
// ---------------------------------------------------------------------------
__global__ __launch_bounds__(256) void qkv_mfma_kernel(
    const u16* __restrict__ hsb,
    const u16* __restrict__ WqT, const float* __restrict__ bq,
    const u16* __restrict__ WkT, const float* __restrict__ bk,
    const u16* __restrict__ WvT, const float* __restrict__ bv,
    u16* __restrict__ qo, u16* __restrict__ ko, u16* __restrict__ vo)
{
    const u16* Wt; const float* bias; u16* out;
    if (blockIdx.z == 0)      { Wt = WqT; bias = bq; out = qo; }
    else if (blockIdx.z == 1) { Wt = WkT; bias = bk; out = ko; }
    else                      { Wt = WvT; bias = bv; out = vo; }

    __shared__ __align__(16) u16 As[64*64];
    __shared__ __align__(16) u16 Bs[64*64];
    const int tid = threadIdx.x;
    const int w = tid >> 6, lane = tid & 63, lh = lane & 15, g = lane >> 4;
    const int wm = w >> 1, wn = w & 1;
    const int row0 = blockIdx.y * 64, col0 = blockIdx.x * 64;

    f32x4 acc[2][2];
    #pragma unroll
    for (int i = 0; i < 2; ++i)
        #pragma unroll
        for (int j = 0; j < 2; ++j) acc[i][j] = (f32x4){0.f,0.f,0.f,0.f};

    for (int k0 = 0; k0 < EMB; k0 += 64) {
        __syncthreads();
        #pragma unroll
        for (int i = 0; i < 2; ++i) {
            int idx = tid + 256*i;
            int r = idx >> 3, c = idx & 7;
            float4 a4 = *(const float4*)(hsb + (size_t)(row0 + r)*EMB + k0 + c*8);
            *(float4*)(As + ((size_t)r*8 + (c ^ (r & 7)))*8) = a4;
            float4 b4 = *(const float4*)(Wt + (size_t)(col0 + r)*EMB + k0 + c*8);
            *(float4*)(Bs + ((size_t)r*8 + (c ^ (r & 7)))*8) = b4;
        }
        __syncthreads();
        bf16x8 af[2][2], bfr[2][2];
        #pragma unroll
        for (int mt = 0; mt < 2; ++mt)
            #pragma unroll
            for (int kk = 0; kk < 2; ++kk) {
                int r = wm*32 + mt*16 + lh;
                af[mt][kk] = *(const bf16x8*)(As + ((size_t)r*8 + ((kk*4+g) ^ (lh & 7)))*8);
            }
        #pragma unroll
        for (int nt = 0; nt < 2; ++nt)
            #pragma unroll
            for (int kk = 0; kk < 2; ++kk) {
                int r = wn*32 + nt*16 + lh;
                bfr[nt][kk] = *(const bf16x8*)(Bs + ((size_t)r*8 + ((kk*4+g) ^ (lh & 7)))*8);
            }
        #pragma unroll
        for (int mt = 0; mt < 2; ++mt)
            #pragma unroll
            for (int nt = 0; nt < 2; ++nt)
                #pragma unroll
                for (int kk = 0; kk < 2; ++kk)
                    acc[mt][nt] = MFMA16(af[mt][kk], bfr[nt][kk], acc[mt][nt]);
    }

    #pragma unroll
    for (int mt = 0; mt < 2; ++mt)
        #pragma unroll
        for (int nt = 0; nt < 2; ++nt)
            #pragma unroll
            for (int r = 0; r < 4; ++r) {
                int tt = row0 + wm*32 + mt*16 + g*4 + r;
                int o  = col0 + wn*32 + nt*16 + lh;
                float val = acc[mt][nt][r] + bias[o];
                int b = tt >> 11, s = tt & (S_LEN - 1);
                int h = o / HD, d = o - h*HD;
                out[((size_t)(b*NH + h)*S_LEN + s)*HD + d] = f2bf(val);
            }
}

// ---------------------------------------------------------------------------
// V transpose: vb[B,H,S,D] bf16 -> vt[B,H,D,S] bf16 (unchanged)
// ---------------------------------------------------------------------------
__global__ __launch_bounds__(256) void vtrans_kernel(
    const u16* __restrict__ vb, u16* __restrict__ vt)
{
    const int bh = blockIdx.y;
    const int s0 = blockIdx.x * 64;
    __shared__ __align__(16) u16 T[64*96];
    const int t = threadIdx.x;
    #pragma unroll
    for (int i = 0; i < 3; ++i) {
        int idx = t + 256*i;
        int s = idx / 12, c = idx % 12;
        float4 v = *(const float4*)(vb + ((size_t)bh*S_LEN + s0 + s)*HD + c*8);
        *(float4*)(T + ((size_t)s*12 + c)*8) = v;
    }
    __syncthreads();
    #pragma unroll
    for (int i = 0; i < 3; ++i) {
        int idx = t + 256*i;
        int d = idx >> 3, c = idx & 7;
        U16x8 o;
        #pragma unroll
        for (int e = 0; e < 8; ++e) o.u[e] = T[(size_t)(c*8+e)*HD + d];
        *(float4*)(vt + ((size_t)bh*HD + d)*S_LEN + s0 + c*8) = o.f4;
    }
}

// ---------------------------------------------------------------------------
// Pass 1 (scores): no-max softmax. Writes u = exp(s) bf16 and row-sum l.
// 32 q-rows/block, grid (64,16). dist/ang via NORMAL cached loads (8-way
// head reuse through L3 — nt hint was the round-6 regression). T14: loads
// issued at loop top, consumed post-barrier; K reg-staged one tile ahead.
// ---------------------------------------------------------------------------
__global__ __launch_bounds__(256) void scores_mfma_kernel(
    const u16* __restrict__ qbf, const u16* __restrict__ kbf,
    const float* __restrict__ dist, const float* __restrict__ ang,
    const float* __restrict__ mask,
    const float* __restrict__ pdw, const float* __restrict__ pdb,
    const float* __restrict__ paw, const float* __restrict__ pab,
    u16* __restrict__ ubuf, float* __restrict__ lrow)
{
    const int bh = blockIdx.y, b = bh >> 3;
    const int q0 = blockIdx.x * 32;
    const int tid = threadIdx.x;
    const int lane = tid & 63, w = tid >> 6, lh = lane & 15, g = lane >> 4;
    const int wr = (w & 1) * 16;
    const int wc = (w >> 1) * 32;

    __shared__ __align__(16) u16 Qs[32*96];
    __shared__ __align__(16) u16 Ks[64*96];
    __shared__ __align__(16) float Sf[32*68];

    // stage Q tile (32 rows x 12 chunks), swizzle c ^= (r>>1)&3
    #pragma unroll
    for (int i = 0; i < 2; ++i) {
        int idx = tid + 256*i;
        if (idx < 384) {
            int r = idx / 12, c = idx % 12;
            float4 v = *(const float4*)(qbf + ((size_t)bh*S_LEN + q0 + r)*HD + c*8);
            *(float4*)(Qs + ((size_t)r*12 + (c ^ ((r >> 1) & 3)))*8) = v;
        }
    }
    // prologue: stage K tile kt=0
    #pragma unroll
    for (int i = 0; i < 3; ++i) {
        int idx = tid + 256*i;
        int r = idx / 12, c = idx % 12;
        float4 v = *(const float4*)(kbf + ((size_t)bh*S_LEN + r)*HD + c*8);
        *(float4*)(Ks + ((size_t)r*12 + (c ^ ((r >> 1) & 3)))*8) = v;
    }
    __syncthreads();

    bf16x8 qf[3];
    #pragma unroll
    for (int kk = 0; kk < 3; ++kk) {
        int r = wr + lh;
        qf[kk] = *(const bf16x8*)(Qs + ((size_t)r*12 + ((kk*4+g) ^ ((r >> 1) & 3)))*8);
    }

    const float DW = *pdw, AW = *paw, CB = *pdb + *pab;
    const int trow = tid >> 4;
    const int c4   = tid & 15;
    const size_t drow0 = ((size_t)b*S_LEN + q0 + trow)*S_LEN;
    const size_t drow1 = drow0 + (size_t)16*S_LEN;

    float l0 = 0.f, l1 = 0.f;            // per-thread partial row sums

    for (int kt = 0; kt < 32; ++kt) {
        int coff = kt*64 + c4*4;
        // issue dist/ang/mask loads for this kt (normal cached loads —
        // 8-way reuse across heads lives in L3; consumed post-barrier)
        float4 d40 = *(const float4*)(dist + drow0 + coff);
        float4 g40 = *(const float4*)(ang  + drow0 + coff);
        float4 d41 = *(const float4*)(dist + drow1 + coff);
        float4 g41 = *(const float4*)(ang  + drow1 + coff);
        float4 m4  = *(const float4*)(mask + b*S_LEN + coff);
        // issue K loads for kt+1 into regs
        float4 kreg[3];
        if (kt < 31) {
            #pragma unroll
            for (int i = 0; i < 3; ++i) {
                int idx = tid + 256*i;
                int r = idx / 12, c = idx - r*12;
                kreg[i] = *(const float4*)(kbf + ((size_t)bh*S_LEN + (kt+1)*64 + r)*HD + c*8);
            }
        }

        // MFMA over current Ks
        f32x4 acc[2];
        #pragma unroll
        for (int ct = 0; ct < 2; ++ct) acc[ct] = (f32x4){0.f,0.f,0.f,0.f};
        #pragma unroll
        for (int ct = 0; ct < 2; ++ct)
            #pragma unroll
            for (int kk = 0; kk < 3; ++kk) {
                int kr = wc + ct*16 + lh;
                bf16x8 kf = *(const bf16x8*)(Ks + ((size_t)kr*12 + ((kk*4+g) ^ ((kr >> 1) & 3)))*8);
                acc[ct] = MFMA16(qf[kk], kf, acc[ct]);
            }
        #pragma unroll
        for (int ct = 0; ct < 2; ++ct)
            #pragma unroll
            for (int r = 0; r < 4; ++r)
                Sf[(wr + g*4 + r)*68 + wc + ct*16 + lh] = acc[ct][r];
        __syncthreads();

        // epilogue: s = acc*scl + bias + mask; u = exp(s); accumulate l
        float ma0 = (1.f - m4.x) * -10000.f, ma1 = (1.f - m4.y) * -10000.f;
        float ma2 = (1.f - m4.z) * -10000.f, ma3 = (1.f - m4.w) * -10000.f;
        {
            float4 s4 = *(const float4*)&Sf[trow*68 + c4*4];
            float e0 = __expf(s4.x*RSQRT_D + DW*d40.x + AW*g40.x + CB + ma0);
            float e1 = __expf(s4.y*RSQRT_D + DW*d40.y + AW*g40.y + CB + ma1);
            float e2 = __expf(s4.z*RSQRT_D + DW*d40.z + AW*g40.z + CB + ma2);
            float e3 = __expf(s4.w*RSQRT_D + DW*d40.w + AW*g40.w + CB + ma3);
            l0 += (e0 + e1) + (e2 + e3);
            U16x4 uk;
            uk.u[0] = f2bf(e0); uk.u[1] = f2bf(e1); uk.u[2] = f2bf(e2); uk.u[3] = f2bf(e3);
            *(uint2*)(ubuf + ((size_t)bh*S_LEN + q0 + trow)*S_LEN + coff) = uk.v2;
        }
        {
            float4 s4 = *(const float4*)&Sf[(trow+16)*68 + c4*4];
            float e0 = __expf(s4.x*RSQRT_D + DW*d41.x + AW*g41.x + CB + ma0);
            float e1 = __expf(s4.y*RSQRT_D + DW*d41.y + AW*g41.y + CB + ma1);
            float e2 = __expf(s4.z*RSQRT_D + DW*d41.z + AW*g41.z + CB + ma2);
            float e3 = __expf(s4.w*RSQRT_D + DW*d41.w + AW*g41.w + CB + ma3);
            l1 += (e0 + e1) + (e2 + e3);
            U16x4 uk;
            uk.u[0] = f2bf(e0); uk.u[1] = f2bf(e1); uk.u[2] = f2bf(e2); uk.u[3] = f2bf(e3);
            *(uint2*)(ubuf + ((size_t)bh*S_LEN + q0 + trow + 16)*S_LEN + coff) = uk.v2;
        }
        // ds_write next K tile
        if (kt < 31) {
            #pragma unroll
            for (int i = 0; i < 3; ++i) {
                int idx = tid + 256*i;
                int r = idx / 12, c = idx - r*12;
                *(float4*)(Ks + ((size_t)r*12 + (c ^ ((r >> 1) & 3)))*8) = kreg[i];
            }
        }
        __syncthreads();
    }

    // one-time row-sum reduction across the 16 lanes owning each row
    #pragma unroll
    for (int off = 1; off <= 8; off <<= 1) {
        l0 += __shfl_xor(l0, off);
        l1 += __shfl_xor(l1, off);
    }
    if (c4 == 0) {
        lrow[(bh << 11) + q0 + trow]      = l0;
        lrow[(bh << 11) + q0 + trow + 16] = l1;
    }
}

// ---------------------------------------------------------------------------
// Pass 2 (PV + probs): p = u * invl (no expf). P-operand = raw u bits (bf16
// already); ctx scaled by invl at the end. grid (64,16), block 256.
// probs stores stay nontemporal (write-once, never re-read).
// ---------------------------------------------------------------------------
__global__ __launch_bounds__(256) void pv_mfma_kernel(
    const u16* __restrict__ ubuf, const float* __restrict__ lrow,
    const u16* __restrict__ vt,
    float* __restrict__ probs, u16* __restrict__ ctxb)
{
    const int bh = blockIdx.y, b = bh >> 3, h = bh & 7;
    const int q0 = blockIdx.x * 32;
    const int tid = threadIdx.x;
    const int lane = tid & 63, w = tid >> 6, lh = lane & 15, g = lane >> 4;
    const int wr = (w & 1) * 16;        // wave's q-row base
    const int wd = (w >> 1) * 48;       // wave's d-col base

    __shared__ __align__(16) u16 Ps[32*64];
    __shared__ __align__(16) u16 Vs[96*64];

    const int trow = tid >> 4, c4 = tid & 15;
    const float il0 = 1.0f / lrow[(bh << 11) + q0 + trow];
    const float il1 = 1.0f / lrow[(bh << 11) + q0 + trow + 16];
    const u16* urow0 = ubuf + ((size_t)bh*S_LEN + q0 + trow)*S_LEN;
    const u16* urow1 = urow0 + (size_t)16*S_LEN;
    float*     prow0 = probs + ((size_t)bh*S_LEN + q0 + trow)*S_LEN;
    float*     prow1 = prow0 + (size_t)16*S_LEN;
    const int swzoff = ((trow*8 + ((c4 >> 1) ^ (trow & 7)))*8 + (c4 & 1)*4);

    f32x4 acc[3];
    #pragma unroll
    for (int j = 0; j < 3; ++j) acc[j] = (f32x4){0.f,0.f,0.f,0.f};

    // prologue loads for kt=0
    uint2 ua = *(const uint2*)(urow0);
    uint2 ub = *(const uint2*)(urow1);
    float4 vreg[3];
    #pragma unroll
    for (int i = 0; i < 3; ++i) {
        int idx = tid + 256*i;
        int vr = idx >> 3, c = idx & 7;
        vreg[i] = *(const float4*)(vt + ((size_t)bh*HD + vr)*S_LEN + c*8);
    }

    for (int kt = 0; kt < 32; ++kt) {
        int coff = kt*64 + c4*4;
        // stage phase: probs writes from u regs; Ps (raw bit copy); Vs
        {
            f32x4 p;
            p[0] = bf2f(ua.x & 0xffffu)*il0; p[1] = bf2f(ua.x >> 16)*il0;
            p[2] = bf2f(ua.y & 0xffffu)*il0; p[3] = bf2f(ua.y >> 16)*il0;
            __builtin_nontemporal_store(p, (f32x4*)(prow0 + coff));
            *(uint2*)(Ps + swzoff) = ua;

            p[0] = bf2f(ub.x & 0xffffu)*il1; p[1] = bf2f(ub.x >> 16)*il1;
            p[2] = bf2f(ub.y & 0xffffu)*il1; p[3] = bf2f(ub.y >> 16)*il1;
            __builtin_nontemporal_store(p, (f32x4*)(prow1 + coff));
            *(uint2*)(Ps + (16*8*8) + swzoff) = ub;
        }
        #pragma unroll
        for (int i = 0; i < 3; ++i) {
            int idx = tid + 256*i;
            int vr = idx >> 3, c = idx & 7;
            *(float4*)(Vs + ((size_t)vr*8 + (c ^ (vr & 7)))*8) = vreg[i];
        }
        __syncthreads();

        // issue loads for kt+1 (hide under MFMA)
        if (kt < 31) {
            int coff1 = (kt+1)*64 + c4*4;
            ua = *(const uint2*)(urow0 + coff1);
            ub = *(const uint2*)(urow1 + coff1);
            #pragma unroll
            for (int i = 0; i < 3; ++i) {
                int idx = tid + 256*i;
                int vr = idx >> 3, c = idx & 7;
                vreg[i] = *(const float4*)(vt + ((size_t)bh*HD + vr)*S_LEN + (kt+1)*64 + c*8);
            }
        }

        bf16x8 pa[2];
        #pragma unroll
        for (int kk = 0; kk < 2; ++kk) {
            int r = wr + lh;
            pa[kk] = *(const bf16x8*)(Ps + ((size_t)r*8 + ((kk*4+g) ^ (r & 7)))*8);
        }
        #pragma unroll
        for (int j = 0; j < 3; ++j)
            #pragma unroll
            for (int kk = 0; kk < 2; ++kk) {
                int vr = wd + j*16 + lh;
                bf16x8 vf = *(const bf16x8*)(Vs + ((size_t)vr*8 + ((kk*4+g) ^ (vr & 7)))*8);
                acc[j] = MFMA16(pa[kk], vf, acc[j]);
            }
        __syncthreads();
    }

    // final scale by invl per accumulator row, then store ctx
    float ils[4];
    #pragma unroll
    for (int r = 0; r < 4; ++r)
        ils[r] = 1.0f / lrow[(bh << 11) + q0 + wr + g*4 + r];
    #pragma unroll
    for (int j = 0; j < 3; ++j)
        #pragma unroll
        for (int r = 0; r < 4; ++r) {
            int qrow = q0 + wr + g*4 + r;
            ctxb[((size_t)(b*S_LEN + qrow))*EMB + h*HD + wd + j*16 + lh] = f2bf(acc[j][r] * ils[r]);
        }
}

// ---------------------------------------------------------------------------
// Output proj MFMA (unchanged)
// ---------------------------------------------------------------------------
__global__ __launch_bounds__(256) void out_mfma_kernel(
    const u16* __restrict__ ctxb, const u16* __restrict__ WoT,
    const float* __restrict__ bo, const float* __restrict__ hs,
    float* __restrict__ res)
{
    __shared__ __align__(16) u16 As[64*64];
    __shared__ __align__(16) u16 Bs[64*64];
    const int tid = threadIdx.x;
    const int w = tid >> 6, lane = tid & 63, lh = lane & 15, g = lane >> 4;
    const int wm = w >> 1, wn = w & 1;
    const int row0 = blockIdx.y * 64, col0 = blockIdx.x * 64;

    f32x4 acc[2][2];
    #pragma unroll
    for (int i = 0; i < 2; ++i)
        #pragma unroll
        for (int j = 0; j < 2; ++j) acc[i][j] = (f32x4){0.f,0.f,0.f,0.f};

    for (int k0 = 0; k0 < EMB; k0 += 64) {
        __syncthreads();
        #pragma unroll
        for (int i = 0; i < 2; ++i) {
            int idx = tid + 256*i;
            int r = idx >> 3, c = idx & 7;
            float4 a4 = *(const float4*)(ctxb + (size_t)(row0 + r)*EMB + k0 + c*8);
            *(float4*)(As + ((size_t)r*8 + (c ^ (r & 7)))*8) = a4;
            float4 b4 = *(const float4*)(WoT + (size_t)(col0 + r)*EMB + k0 + c*8);
            *(float4*)(Bs + ((size_t)r*8 + (c ^ (r & 7)))*8) = b4;
        }
        __syncthreads();
        bf16x8 af[2][2], bfr[2][2];
        #pragma unroll
        for (int mt = 0; mt < 2; ++mt)
            #pragma unroll
            for (int kk = 0; kk < 2; ++kk) {
                int r = wm*32 + mt*16 + lh;
                af[mt][kk] = *(const bf16x8*)(As + ((size_t)r*8 + ((kk*4+g) ^ (lh & 7)))*8);
            }
        #pragma unroll
        for (int nt = 0; nt < 2; ++nt)
            #pragma unroll
            for (int kk = 0; kk < 2; ++kk) {
                int r = wn*32 + nt*16 + lh;
                bfr[nt][kk] = *(const bf16x8*)(Bs + ((size_t)r*8 + ((kk*4+g) ^ (lh & 7)))*8);
            }
        #pragma unroll
        for (int mt = 0; mt < 2; ++mt)
            #pragma unroll
            for (int nt = 0; nt < 2; ++nt)
                #pragma unroll
                for (int kk = 0; kk < 2; ++kk)
                    acc[mt][nt] = MFMA16(af[mt][kk], bfr[nt][kk], acc[mt][nt]);
    }

    #pragma unroll
    for (int mt = 0; mt < 2; ++mt)
        #pragma unroll
        for (int nt = 0; nt < 2; ++nt)
            #pragma unroll
            for (int r = 0; r < 4; ++r) {
                int tt = row0 + wm*32 + mt*16 + g*4 + r;
                int o  = col0 + wn*32 + nt*16 + lh;
                res[(size_t)tt*EMB + o] = acc[mt][nt][r] + bo[o] + hs[(size_t)tt*EMB + o];
            }
}

// ---------------------------------------------------------------------------
// LayerNorm in place over last dim 768. grid NTOK, block 256.
// ---------------------------------------------------------------------------
__device__ __forceinline__ float block_sum256(float v, float* red) {
    #pragma unroll
    for (int off = 32; off > 0; off >>= 1) v += __shfl_down(v, off);
    int lane = threadIdx.x & 63, w = threadIdx.x >> 6;
    __syncthreads();
    if (lane == 0) red[w] = v;
    __syncthreads();
    return red[0] + red[1] + red[2] + red[3];
}

__global__ __launch_bounds__(256) void ln_kernel(
    float* __restrict__ res, const float* __restrict__ gamma, const float* __restrict__ beta)
{
    const int t = blockIdx.x;
    float* row = res + (size_t)t * EMB;
    const int tid = threadIdx.x;
    __shared__ float red[4];

    float x0 = row[tid], x1 = row[tid + 256], x2 = row[tid + 512];
    float s = block_sum256(x0 + x1 + x2, red);
    float mu = s * (1.0f / (float)EMB);
    float d0 = x0 - mu, d1 = x1 - mu, d2 = x2 - mu;
    float sq = block_sum256(d0*d0 + d1*d1 + d2*d2, red);
    float var = sq * (1.0f / (float)EMB);
    float scale = rsqrtf(var + 1e-5f);

    row[tid]       = d0 * scale * gamma[tid]       + beta[tid];
    row[tid + 256] = d1 * scale * gamma[tid + 256] + beta[tid + 256];
    row[tid + 512] = d2 * scale * gamma[tid + 512] + beta[tid + 512];
}

// ---------------------------------------------------------------------------
extern "C" void kernel_launch(void* const* d_in, const int* in_sizes, int n_in,
                              void* d_out, int out_size, void* d_ws, size_t ws_size,
                              hipStream_t stream)
{
    (void)in_sizes; (void)n_in; (void)out_size; (void)ws_size;

    const float* hs   = (const float*)d_in[0];
    const float* dist = (const float*)d_in[1];
    const float* ang  = (const float*)d_in[2];
    const float* mask = (const float*)d_in[3];
    const float* Wq = (const float*)d_in[4];  const float* bq = (const float*)d_in[5];
    const float* Wk = (const float*)d_in[6];  const float* bk = (const float*)d_in[7];
    const float* Wv = (const float*)d_in[8];  const float* bv = (const float*)d_in[9];
    const float* dw = (const float*)d_in[10]; const float* db = (const float*)d_in[11];
    const float* aw = (const float*)d_in[12]; const float* ab = (const float*)d_in[13];
    const float* Wo = (const float*)d_in[14]; const float* bo = (const float*)d_in[15];
    const float* gamma = (const float*)d_in[16]; const float* beta = (const float*)d_in[17];

    float* out   = (float*)d_out;                      // [B,S,E]
    float* probs = out + (size_t)NTOK * EMB;           // [B,H,S,S]

    u16* hsb = (u16*)d_ws;
    u16* WqT = hsb + (size_t)NTOK*EMB;
    u16* WkT = WqT + (size_t)EMB*EMB;
    u16* WvT = WkT + (size_t)EMB*EMB;
    u16* WoT = WvT + (size_t)EMB*EMB;
    u16* qb  = WoT + (size_t)EMB*EMB;
    u16* kb  = qb + (size_t)NTOK*EMB;
    u16* vb  = kb + (size_t)NTOK*EMB;
    u16* vtb = vb + (size_t)NTOK*EMB;
    u16* ctxb = qb;                                    // reuse q region after scores
    float* lrow = (float*)(vtb + (size_t)NTOK*EMB);
    u16*   ubuf = (u16*)(lrow + (size_t)BATCH*NH*S_LEN);   // [bh][2048][2048] bf16 = 134 MB

    cvt_bf16_kernel<<<dim3(NTOK*EMB/4/256), dim3(256), 0, stream>>>(hs, hsb, NTOK*EMB/4);
    transcvt_kernel<<<dim3(12,12), dim3(256), 0, stream>>>(Wq, WqT);
    transcvt_kernel<<<dim3(12,12), dim3(256), 0, stream>>>(Wk, WkT);
    transcvt_kernel<<<dim3(12,12), dim3(256), 0, stream>>>(Wv, WvT);
    transcvt_kernel<<<dim3(12,12), dim3(256), 0, stream>>>(Wo, WoT);

    qkv_mfma_kernel<<<dim3(EMB/64, NTOK/64, 3), dim3(256), 0, stream>>>(
        hsb, WqT, bq, WkT, bk, WvT, bv, qb, kb, vb);

    vtrans_kernel<<<dim3(S_LEN/64, BATCH*NH), dim3(256), 0, stream>>>(vb, vtb);

    scores_mfma_kernel<<<dim3(S_LEN/32, BATCH*NH), dim3(256), 0, stream>>>(
        qb, kb, dist, ang, mask, dw, db, aw, ab, ubuf, lrow);

    pv_mfma_kernel<<<dim3(S_LEN/32, BATCH*NH), dim3(256), 0, stream>>>(
        ubuf, lrow, vtb, probs, ctxb);

    out_mfma_kernel<<<dim3(EMB/64, NTOK/64), dim3(256), 0, stream>>>(
        ctxb, WoT, bo, hs, out);

    ln_kernel<<<dim3(NTOK), dim3(256), 0, stream>>>(out, gamma, beta);
}

// Round 8
// 335.815 us; speedup vs baseline: 1.1717x; 1.1717x over previous
//
#include <hip/hip_runtime.h>
#include <math.h>

#define S_LEN 2048
#define BATCH 2
#define EMB 768
#define NH 8
#define HD 96
#define NTOK (BATCH*S_LEN)
#define RSQRT_D 0.10206207261596575f   // 1/sqrt(96)

typedef unsigned short u16;
typedef __attribute__((ext_vector_type(8))) short bf16x8;
typedef __attribute__((ext_vector_type(4))) float f32x4;

#define MFMA16(a,b,c) __builtin_amdgcn_mfma_f32_16x16x32_bf16(a,b,c,0,0,0)

__device__ __forceinline__ u16 f2bf(float f){
    unsigned u = __float_as_uint(f);
    return (u16)((u + 0x7fffu + ((u>>16)&1u)) >> 16);
}
__device__ __forceinline__ float bf2f(unsigned u){
    return __uint_as_float(u << 16);
}

union U16x8 { u16 u[8]; float4 f4; };
union U16x4 { u16 u[4]; uint2 v2; };

// ---------------------------------------------------------------------------
// f32 -> bf16 elementwise convert (vectorized x4)
// ---------------------------------------------------------------------------
__global__ __launch_bounds__(256) void cvt_bf16_kernel(
    const float* __restrict__ src, u16* __restrict__ dst, int n4)
{
    int i = blockIdx.x * 256 + threadIdx.x;
    if (i < n4) {
        float4 v = ((const float4*)src)[i];
        U16x4 o;
        o.u[0] = f2bf(v.x); o.u[1] = f2bf(v.y); o.u[2] = f2bf(v.z); o.u[3] = f2bf(v.w);
        *(uint2*)(dst + (size_t)i*4) = o.v2;
    }
}

// ---------------------------------------------------------------------------
// W[768][768] f32 -> Wt[n][k] bf16 (transpose + convert). grid (12,12), 256thr
// ---------------------------------------------------------------------------
__global__ __launch_bounds__(256) void transcvt_kernel(
    const float* __restrict__ W, u16* __restrict__ Wt)
{
    __shared__ float T[64][65];
    const int t = threadIdx.x;
    const int k0 = blockIdx.y * 64, n0 = blockIdx.x * 64;
    #pragma unroll
    for (int i = 0; i < 4; ++i) {
        int idx = t + 256*i;
        int r = idx >> 4, c4 = idx & 15;
        float4 v = *(const float4*)(W + (size_t)(k0 + r)*EMB + n0 + c4*4);
        T[r][c4*4+0] = v.x; T[r][c4*4+1] = v.y; T[r][c4*4+2] = v.z; T[r][c4*4+3] = v.w;
    }
    __syncthreads();
    #pragma unroll
    for (int i = 0; i < 2; ++i) {
        int idx = t + 256*i;
        int n = idx >> 3, c = idx & 7;
        U16x8 o;
        #pragma unroll
        for (int e = 0; e < 8; ++e) o.u[e] = f2bf(T[c*8+e][n]);
        *(float4*)(Wt + (size_t)(n0 + n)*EMB + k0 + c*8) = o.f4;
    }
}

// ---------------------------------------------------------------------------
// QKV projection MFMA (unchanged)
// ---------------------------------------------------------------------------
__global__ __launch_bounds__(256) void qkv_mfma_kernel(
    const u16* __restrict__ hsb,
    const u16* __restrict__ WqT, const float* __restrict__ bq,
    const u16* __restrict__ WkT, const float* __restrict__ bk,
    const u16* __restrict__ WvT, const float* __restrict__ bv,
    u16* __restrict__ qo, u16* __restrict__ ko, u16* __restrict__ vo)
{
    const u16* Wt; const float* bias; u16* out;
    if (blockIdx.z == 0)      { Wt = WqT; bias = bq; out = qo; }
    else if (blockIdx.z == 1) { Wt = WkT; bias = bk; out = ko; }
    else                      { Wt = WvT; bias = bv; out = vo; }

    __shared__ __align__(16) u16 As[64*64];
    __shared__ __align__(16) u16 Bs[64*64];
    const int tid = threadIdx.x;
    const int w = tid >> 6, lane = tid & 63, lh = lane & 15, g = lane >> 4;
    const int wm = w >> 1, wn = w & 1;
    const int row0 = blockIdx.y * 64, col0 = blockIdx.x * 64;

    f32x4 acc[2][2];
    #pragma unroll
    for (int i = 0; i < 2; ++i)
        #pragma unroll
        for (int j = 0; j < 2; ++j) acc[i][j] = (f32x4){0.f,0.f,0.f,0.f};

    for (int k0 = 0; k0 < EMB; k0 += 64) {
        __syncthreads();
        #pragma unroll
        for (int i = 0; i < 2; ++i) {
            int idx = tid + 256*i;
            int r = idx >> 3, c = idx & 7;
            float4 a4 = *(const float4*)(hsb + (size_t)(row0 + r)*EMB + k0 + c*8);
            *(float4*)(As + ((size_t)r*8 + (c ^ (r & 7)))*8) = a4;
            float4 b4 = *(const float4*)(Wt + (size_t)(col0 + r)*EMB + k0 + c*8);
            *(float4*)(Bs + ((size_t)r*8 + (c ^ (r & 7)))*8) = b4;
        }
        __syncthreads();
        bf16x8 af[2][2], bfr[2][2];
        #pragma unroll
        for (int mt = 0; mt < 2; ++mt)
            #pragma unroll
            for (int kk = 0; kk < 2; ++kk) {
                int r = wm*32 + mt*16 + lh;
                af[mt][kk] = *(const bf16x8*)(As + ((size_t)r*8 + ((kk*4+g) ^ (lh & 7)))*8);
            }
        #pragma unroll
        for (int nt = 0; nt < 2; ++nt)
            #pragma unroll
            for (int kk = 0; kk < 2; ++kk) {
                int r = wn*32 + nt*16 + lh;
                bfr[nt][kk] = *(const bf16x8*)(Bs + ((size_t)r*8 + ((kk*4+g) ^ (lh & 7)))*8);
            }
        #pragma unroll
        for (int mt = 0; mt < 2; ++mt)
            #pragma unroll
            for (int nt = 0; nt < 2; ++nt)
                #pragma unroll
                for (int kk = 0; kk < 2; ++kk)
                    acc[mt][nt] = MFMA16(af[mt][kk], bfr[nt][kk], acc[mt][nt]);
    }

    #pragma unroll
    for (int mt = 0; mt < 2; ++mt)
        #pragma unroll
        for (int nt = 0; nt < 2; ++nt)
            #pragma unroll
            for (int r = 0; r < 4; ++r) {
                int tt = row0 + wm*32 + mt*16 + g*4 + r;
                int o  = col0 + wn*32 + nt*16 + lh;
                float val = acc[mt][nt][r] + bias[o];
                int b = tt >> 11, s = tt & (S_LEN - 1);
                int h = o / HD, d = o - h*HD;
                out[((size_t)(b*NH + h)*S_LEN + s)*HD + d] = f2bf(val);
            }
}

// ---------------------------------------------------------------------------
// V transpose: vb[B,H,S,D] bf16 -> vt[B,H,D,S] bf16 (unchanged)
// ---------------------------------------------------------------------------
__global__ __launch_bounds__(256) void vtrans_kernel(
    const u16* __restrict__ vb, u16* __restrict__ vt)
{
    const int bh = blockIdx.y;
    const int s0 = blockIdx.x * 64;
    __shared__ __align__(16) u16 T[64*96];
    const int t = threadIdx.x;
    #pragma unroll
    for (int i = 0; i < 3; ++i) {
        int idx = t + 256*i;
        int s = idx / 12, c = idx % 12;
        float4 v = *(const float4*)(vb + ((size_t)bh*S_LEN + s0 + s)*HD + c*8);
        *(float4*)(T + ((size_t)s*12 + c)*8) = v;
    }
    __syncthreads();
    #pragma unroll
    for (int i = 0; i < 3; ++i) {
        int idx = t + 256*i;
        int d = idx >> 3, c = idx & 7;
        U16x8 o;
        #pragma unroll
        for (int e = 0; e < 8; ++e) o.u[e] = T[(size_t)(c*8+e)*HD + d];
        *(float4*)(vt + ((size_t)bh*HD + d)*S_LEN + s0 + c*8) = o.f4;
    }
}

// ---------------------------------------------------------------------------
// Pass 1 (scores): no-max softmax, round-4 staging structure (stage K
// global->LDS at loop top in one phase; plain cached loads; 2 barriers/iter).
// Writes u = exp(s) bf16 and per-row sum l. 32 q-rows/block, grid (64,16).
// ---------------------------------------------------------------------------
__global__ __launch_bounds__(256) void scores_mfma_kernel(
    const u16* __restrict__ qbf, const u16* __restrict__ kbf,
    const float* __restrict__ dist, const float* __restrict__ ang,
    const float* __restrict__ mask,
    const float* __restrict__ pdw, const float* __restrict__ pdb,
    const float* __restrict__ paw, const float* __restrict__ pab,
    u16* __restrict__ ubuf, float* __restrict__ lrow)
{
    const int bh = blockIdx.y, b = bh >> 3;
    const int q0 = blockIdx.x * 32;
    const int tid = threadIdx.x;
    const int lane = tid & 63, w = tid >> 6, lh = lane & 15, g = lane >> 4;
    const int wr = (w & 1) * 16;
    const int wc = (w >> 1) * 32;

    __shared__ __align__(16) u16 Qs[32*96];
    __shared__ __align__(16) u16 Ks[64*96];
    __shared__ __align__(16) float Sf[32*68];

    // stage Q tile (32 rows x 12 chunks), swizzle c ^= (r>>1)&3
    #pragma unroll
    for (int i = 0; i < 2; ++i) {
        int idx = tid + 256*i;
        if (idx < 384) {
            int r = idx / 12, c = idx % 12;
            float4 v = *(const float4*)(qbf + ((size_t)bh*S_LEN + q0 + r)*HD + c*8);
            *(float4*)(Qs + ((size_t)r*12 + (c ^ ((r >> 1) & 3)))*8) = v;
        }
    }
    __syncthreads();

    bf16x8 qf[3];
    #pragma unroll
    for (int kk = 0; kk < 3; ++kk) {
        int r = wr + lh;
        qf[kk] = *(const bf16x8*)(Qs + ((size_t)r*12 + ((kk*4+g) ^ ((r >> 1) & 3)))*8);
    }

    const float DW = *pdw, AW = *paw, CB = *pdb + *pab;
    const int trow = tid >> 4;
    const int c4   = tid & 15;
    const size_t drow0 = ((size_t)b*S_LEN + q0 + trow)*S_LEN;
    const size_t drow1 = drow0 + (size_t)16*S_LEN;

    float l0 = 0.f, l1 = 0.f;            // per-thread partial row sums

    for (int kt = 0; kt < 32; ++kt) {
        int coff = kt*64 + c4*4;
        // issue dist/ang/mask loads for this kt (plain cached; consumed in
        // the epilogue after barrier 2 — latency hides under stage+MFMA)
        float4 d40 = *(const float4*)(dist + drow0 + coff);
        float4 g40 = *(const float4*)(ang  + drow0 + coff);
        float4 d41 = *(const float4*)(dist + drow1 + coff);
        float4 g41 = *(const float4*)(ang  + drow1 + coff);
        float4 m4  = *(const float4*)(mask + b*S_LEN + coff);
        // stage K tile (64 rows x 12 chunks) global->LDS in one phase
        #pragma unroll
        for (int i = 0; i < 3; ++i) {
            int idx = tid + 256*i;
            int r = idx / 12, c = idx - r*12;
            float4 v = *(const float4*)(kbf + ((size_t)bh*S_LEN + kt*64 + r)*HD + c*8);
            *(float4*)(Ks + ((size_t)r*12 + (c ^ ((r >> 1) & 3)))*8) = v;
        }
        __syncthreads();

        // MFMA over current Ks
        f32x4 acc[2];
        #pragma unroll
        for (int ct = 0; ct < 2; ++ct) acc[ct] = (f32x4){0.f,0.f,0.f,0.f};
        #pragma unroll
        for (int ct = 0; ct < 2; ++ct)
            #pragma unroll
            for (int kk = 0; kk < 3; ++kk) {
                int kr = wc + ct*16 + lh;
                bf16x8 kf = *(const bf16x8*)(Ks + ((size_t)kr*12 + ((kk*4+g) ^ ((kr >> 1) & 3)))*8);
                acc[ct] = MFMA16(qf[kk], kf, acc[ct]);
            }
        #pragma unroll
        for (int ct = 0; ct < 2; ++ct)
            #pragma unroll
            for (int r = 0; r < 4; ++r)
                Sf[(wr + g*4 + r)*68 + wc + ct*16 + lh] = acc[ct][r];
        __syncthreads();

        // epilogue: s = acc*scl + bias + mask; u = exp(s); accumulate l
        float ma0 = (1.f - m4.x) * -10000.f, ma1 = (1.f - m4.y) * -10000.f;
        float ma2 = (1.f - m4.z) * -10000.f, ma3 = (1.f - m4.w) * -10000.f;
        {
            float4 s4 = *(const float4*)&Sf[trow*68 + c4*4];
            float e0 = __expf(s4.x*RSQRT_D + DW*d40.x + AW*g40.x + CB + ma0);
            float e1 = __expf(s4.y*RSQRT_D + DW*d40.y + AW*g40.y + CB + ma1);
            float e2 = __expf(s4.z*RSQRT_D + DW*d40.z + AW*g40.z + CB + ma2);
            float e3 = __expf(s4.w*RSQRT_D + DW*d40.w + AW*g40.w + CB + ma3);
            l0 += (e0 + e1) + (e2 + e3);
            U16x4 uk;
            uk.u[0] = f2bf(e0); uk.u[1] = f2bf(e1); uk.u[2] = f2bf(e2); uk.u[3] = f2bf(e3);
            *(uint2*)(ubuf + ((size_t)bh*S_LEN + q0 + trow)*S_LEN + coff) = uk.v2;
        }
        {
            float4 s4 = *(const float4*)&Sf[(trow+16)*68 + c4*4];
            float e0 = __expf(s4.x*RSQRT_D + DW*d41.x + AW*g41.x + CB + ma0);
            float e1 = __expf(s4.y*RSQRT_D + DW*d41.y + AW*g41.y + CB + ma1);
            float e2 = __expf(s4.z*RSQRT_D + DW*d41.z + AW*g41.z + CB + ma2);
            float e3 = __expf(s4.w*RSQRT_D + DW*d41.w + AW*g41.w + CB + ma3);
            l1 += (e0 + e1) + (e2 + e3);
            U16x4 uk;
            uk.u[0] = f2bf(e0); uk.u[1] = f2bf(e1); uk.u[2] = f2bf(e2); uk.u[3] = f2bf(e3);
            *(uint2*)(ubuf + ((size_t)bh*S_LEN + q0 + trow + 16)*S_LEN + coff) = uk.v2;
        }
        // no barrier here: next iter's Ks write is safe (all MFMAs passed
        // barrier 2), and next Sf write happens after next barrier 1.
    }

    // one-time row-sum reduction across the 16 lanes owning each row
    #pragma unroll
    for (int off = 1; off <= 8; off <<= 1) {
        l0 += __shfl_xor(l0, off);
        l1 += __shfl_xor(l1, off);
    }
    if (c4 == 0) {
        lrow[(bh << 11) + q0 + trow]      = l0;
        lrow[(bh << 11) + q0 + trow + 16] = l1;
    }
}

// ---------------------------------------------------------------------------
// Pass 2 (PV + probs): p = u * invl (no expf), round-4 staging structure,
// plain cached stores. grid (64,16), block 256.
// ---------------------------------------------------------------------------
__global__ __launch_bounds__(256) void pv_mfma_kernel(
    const u16* __restrict__ ubuf, const float* __restrict__ lrow,
    const u16* __restrict__ vt,
    float* __restrict__ probs, u16* __restrict__ ctxb)
{
    const int bh = blockIdx.y, b = bh >> 3, h = bh & 7;
    const int q0 = blockIdx.x * 32;
    const int tid = threadIdx.x;
    const int lane = tid & 63, w = tid >> 6, lh = lane & 15, g = lane >> 4;
    const int wr = (w & 1) * 16;        // wave's q-row base
    const int wd = (w >> 1) * 48;       // wave's d-col base

    __shared__ __align__(16) u16 Ps[32*64];
    __shared__ __align__(16) u16 Vs[96*64];

    const int trow = tid >> 4, c4 = tid & 15;
    const float il0 = 1.0f / lrow[(bh << 11) + q0 + trow];
    const float il1 = 1.0f / lrow[(bh << 11) + q0 + trow + 16];
    const u16* urow0 = ubuf + ((size_t)bh*S_LEN + q0 + trow)*S_LEN;
    const u16* urow1 = urow0 + (size_t)16*S_LEN;
    float*     prow0 = probs + ((size_t)bh*S_LEN + q0 + trow)*S_LEN;
    float*     prow1 = prow0 + (size_t)16*S_LEN;
    const int swzoff = ((trow*8 + ((c4 >> 1) ^ (trow & 7)))*8 + (c4 & 1)*4);

    f32x4 acc[3];
    #pragma unroll
    for (int j = 0; j < 3; ++j) acc[j] = (f32x4){0.f,0.f,0.f,0.f};

    for (int kt = 0; kt < 32; ++kt) {
        if (kt) __syncthreads();        // protect Ps/Vs from prev MFMA readers
        int coff = kt*64 + c4*4;
        // u loads + finish probs + Ps write (raw u bits, already bf16)
        {
            uint2 ua = *(const uint2*)(urow0 + coff);
            uint2 ub = *(const uint2*)(urow1 + coff);
            float4 p;
            p.x = bf2f(ua.x & 0xffffu)*il0; p.y = bf2f(ua.x >> 16)*il0;
            p.z = bf2f(ua.y & 0xffffu)*il0; p.w = bf2f(ua.y >> 16)*il0;
            *(float4*)(prow0 + coff) = p;
            *(uint2*)(Ps + swzoff) = ua;

            p.x = bf2f(ub.x & 0xffffu)*il1; p.y = bf2f(ub.x >> 16)*il1;
            p.z = bf2f(ub.y & 0xffffu)*il1; p.w = bf2f(ub.y >> 16)*il1;
            *(float4*)(prow1 + coff) = p;
            *(uint2*)(Ps + (16*8*8) + swzoff) = ub;
        }
        // stage Vt tile [96][64]
        #pragma unroll
        for (int i = 0; i < 3; ++i) {
            int idx = tid + 256*i;
            int vr = idx >> 3, c = idx & 7;
            float4 v4 = *(const float4*)(vt + ((size_t)bh*HD + vr)*S_LEN + kt*64 + c*8);
            *(float4*)(Vs + ((size_t)vr*8 + (c ^ (vr & 7)))*8) = v4;
        }
        __syncthreads();

        bf16x8 pa[2];
        #pragma unroll
        for (int kk = 0; kk < 2; ++kk) {
            int r = wr + lh;
            pa[kk] = *(const bf16x8*)(Ps + ((size_t)r*8 + ((kk*4+g) ^ (r & 7)))*8);
        }
        #pragma unroll
        for (int j = 0; j < 3; ++j)
            #pragma unroll
            for (int kk = 0; kk < 2; ++kk) {
                int vr = wd + j*16 + lh;
                bf16x8 vf = *(const bf16x8*)(Vs + ((size_t)vr*8 + ((kk*4+g) ^ (vr & 7)))*8);
                acc[j] = MFMA16(pa[kk], vf, acc[j]);
            }
    }

    // final scale by invl per accumulator row, then store ctx
    float ils[4];
    #pragma unroll
    for (int r = 0; r < 4; ++r)
        ils[r] = 1.0f / lrow[(bh << 11) + q0 + wr + g*4 + r];
    #pragma unroll
    for (int j = 0; j < 3; ++j)
        #pragma unroll
        for (int r = 0; r < 4; ++r) {
            int qrow = q0 + wr + g*4 + r;
            ctxb[((size_t)(b*S_LEN + qrow))*EMB + h*HD + wd + j*16 + lh] = f2bf(acc[j][r] * ils[r]);
        }
}

// ---------------------------------------------------------------------------
// Output proj MFMA (unchanged)
// ---------------------------------------------------------------------------
__global__ __launch_bounds__(256) void out_mfma_kernel(
    const u16* __restrict__ ctxb, const u16* __restrict__ WoT,
    const float* __restrict__ bo, const float* __restrict__ hs,
    float* __restrict__ res)
{
    __shared__ __align__(16) u16 As[64*64];
    __shared__ __align__(16) u16 Bs[64*64];
    const int tid = threadIdx.x;
    const int w = tid >> 6, lane = tid & 63, lh = lane & 15, g = lane >> 4;
    const int wm = w >> 1, wn = w & 1;
    const int row0 = blockIdx.y * 64, col0 = blockIdx.x * 64;

    f32x4 acc[2][2];
    #pragma unroll
    for (int i = 0; i < 2; ++i)
        #pragma unroll
        for (int j = 0; j < 2; ++j) acc[i][j] = (f32x4){0.f,0.f,0.f,0.f};

    for (int k0 = 0; k0 < EMB; k0 += 64) {
        __syncthreads();
        #pragma unroll
        for (int i = 0; i < 2; ++i) {
            int idx = tid + 256*i;
            int r = idx >> 3, c = idx & 7;
            float4 a4 = *(const float4*)(ctxb + (size_t)(row0 + r)*EMB + k0 + c*8);
            *(float4*)(As + ((size_t)r*8 + (c ^ (r & 7)))*8) = a4;
            float4 b4 = *(const float4*)(WoT + (size_t)(col0 + r)*EMB + k0 + c*8);
            *(float4*)(Bs + ((size_t)r*8 + (c ^ (r & 7)))*8) = b4;
        }
        __syncthreads();
        bf16x8 af[2][2], bfr[2][2];
        #pragma unroll
        for (int mt = 0; mt < 2; ++mt)
            #pragma unroll
            for (int kk = 0; kk < 2; ++kk) {
                int r = wm*32 + mt*16 + lh;
                af[mt][kk] = *(const bf16x8*)(As + ((size_t)r*8 + ((kk*4+g) ^ (lh & 7)))*8);
            }
        #pragma unroll
        for (int nt = 0; nt < 2; ++nt)
            #pragma unroll
            for (int kk = 0; kk < 2; ++kk) {
                int r = wn*32 + nt*16 + lh;
                bfr[nt][kk] = *(const bf16x8*)(Bs + ((size_t)r*8 + ((kk*4+g) ^ (lh & 7)))*8);
            }
        #pragma unroll
        for (int mt = 0; mt < 2; ++mt)
            #pragma unroll
            for (int nt = 0; nt < 2; ++nt)
                #pragma unroll
                for (int kk = 0; kk < 2; ++kk)
                    acc[mt][nt] = MFMA16(af[mt][kk], bfr[nt][kk], acc[mt][nt]);
    }

    #pragma unroll
    for (int mt = 0; mt < 2; ++mt)
        #pragma unroll
        for (int nt = 0; nt < 2; ++nt)
            #pragma unroll
            for (int r = 0; r < 4; ++r) {
                int tt = row0 + wm*32 + mt*16 + g*4 + r;
                int o  = col0 + wn*32 + nt*16 + lh;
                res[(size_t)tt*EMB + o] = acc[mt][nt][r] + bo[o] + hs[(size_t)tt*EMB + o];
            }
}

// ---------------------------------------------------------------------------
// LayerNorm in place over last dim 768. grid NTOK, block 256.
// ---------------------------------------------------------------------------
__device__ __forceinline__ float block_sum256(float v, float* red) {
    #pragma unroll
    for (int off = 32; off > 0; off >>= 1) v += __shfl_down(v, off);
    int lane = threadIdx.x & 63, w = threadIdx.x >> 6;
    __syncthreads();
    if (lane == 0) red[w] = v;
    __syncthreads();
    return red[0] + red[1] + red[2] + red[3];
}

__global__ __launch_bounds__(256) void ln_kernel(
    float* __restrict__ res, const float* __restrict__ gamma, const float* __restrict__ beta)
{
    const int t = blockIdx.x;
    float* row = res + (size_t)t * EMB;
    const int tid = threadIdx.x;
    __shared__ float red[4];

    float x0 = row[tid], x1 = row[tid + 256], x2 = row[tid + 512];
    float s = block_sum256(x0 + x1 + x2, red);
    float mu = s * (1.0f / (float)EMB);
    float d0 = x0 - mu, d1 = x1 - mu, d2 = x2 - mu;
    float sq = block_sum256(d0*d0 + d1*d1 + d2*d2, red);
    float var = sq * (1.0f / (float)EMB);
    float scale = rsqrtf(var + 1e-5f);

    row[tid]       = d0 * scale * gamma[tid]       + beta[tid];
    row[tid + 256] = d1 * scale * gamma[tid + 256] + beta[tid + 256];
    row[tid + 512] = d2 * scale * gamma[tid + 512] + beta[tid + 512];
}

// ---------------------------------------------------------------------------
extern "C" void kernel_launch(void* const* d_in, const int* in_sizes, int n_in,
                              void* d_out, int out_size, void* d_ws, size_t ws_size,
                              hipStream_t stream)
{
    (void)in_sizes; (void)n_in; (void)out_size; (void)ws_size;

    const float* hs   = (const float*)d_in[0];
    const float* dist = (const float*)d_in[1];
    const float* ang  = (const float*)d_in[2];
    const float* mask = (const float*)d_in[3];
    const float* Wq = (const float*)d_in[4];  const float* bq = (const float*)d_in[5];
    const float* Wk = (const float*)d_in[6];  const float* bk = (const float*)d_in[7];
    const float* Wv = (const float*)d_in[8];  const float* bv = (const float*)d_in[9];
    const float* dw = (const float*)d_in[10]; const float* db = (const float*)d_in[11];
    const float* aw = (const float*)d_in[12]; const float* ab = (const float*)d_in[13];
    const float* Wo = (const float*)d_in[14]; const float* bo = (const float*)d_in[15];
    const float* gamma = (const float*)d_in[16]; const float* beta = (const float*)d_in[17];

    float* out   = (float*)d_out;                      // [B,S,E]
    float* probs = out + (size_t)NTOK * EMB;           // [B,H,S,S]

    u16* hsb = (u16*)d_ws;
    u16* WqT = hsb + (size_t)NTOK*EMB;
    u16* WkT = WqT + (size_t)EMB*EMB;
    u16* WvT = WkT + (size_t)EMB*EMB;
    u16* WoT = WvT + (size_t)EMB*EMB;
    u16* qb  = WoT + (size_t)EMB*EMB;
    u16* kb  = qb + (size_t)NTOK*EMB;
    u16* vb  = kb + (size_t)NTOK*EMB;
    u16* vtb = vb + (size_t)NTOK*EMB;
    u16* ctxb = qb;                                    // reuse q region after scores
    float* lrow = (float*)(vtb + (size_t)NTOK*EMB);
    u16*   ubuf = (u16*)(lrow + (size_t)BATCH*NH*S_LEN);   // [bh][2048][2048] bf16 = 134 MB

    cvt_bf16_kernel<<<dim3(NTOK*EMB/4/256), dim3(256), 0, stream>>>(hs, hsb, NTOK*EMB/4);
    transcvt_kernel<<<dim3(12,12), dim3(256), 0, stream>>>(Wq, WqT);
    transcvt_kernel<<<dim3(12,12), dim3(256), 0, stream>>>(Wk, WkT);
    transcvt_kernel<<<dim3(12,12), dim3(256), 0, stream>>>(Wv, WvT);
    transcvt_kernel<<<dim3(12,12), dim3(256), 0, stream>>>(Wo, WoT);

    qkv_mfma_kernel<<<dim3(EMB/64, NTOK/64, 3), dim3(256), 0, stream>>>(
        hsb, WqT, bq, WkT, bk, WvT, bv, qb, kb, vb);

    vtrans_kernel<<<dim3(S_LEN/64, BATCH*NH), dim3(256), 0, stream>>>(vb, vtb);

    scores_mfma_kernel<<<dim3(S_LEN/32, BATCH*NH), dim3(256), 0, stream>>>(
        qb, kb, dist, ang, mask, dw, db, aw, ab, ubuf, lrow);

    pv_mfma_kernel<<<dim3(S_LEN/32, BATCH*NH), dim3(256), 0, stream>>>(
        ubuf, lrow, vtb, probs, ctxb);

    out_mfma_kernel<<<dim3(EMB/64, NTOK/64), dim3(256), 0, stream>>>(
        ctxb, WoT, bo, hs, out);

    ln_kernel<<<dim3(NTOK), dim3(256), 0, stream>>>(out, gamma, beta);
}

// Round 9
// 322.454 us; speedup vs baseline: 1.2203x; 1.0414x over previous
//
#include <hip/hip_runtime.h>
#include <math.h>

#define S_LEN 2048
#define BATCH 2
#define EMB 768
#define NH 8
#define HD 96
#define NTOK (BATCH*S_LEN)
#define RSQRT_D 0.10206207261596575f   // 1/sqrt(96)

typedef unsigned short u16;
typedef __attribute__((ext_vector_type(8))) short bf16x8;
typedef __attribute__((ext_vector_type(4))) float f32x4;

#define MFMA16(a,b,c) __builtin_amdgcn_mfma_f32_16x16x32_bf16(a,b,c,0,0,0)

__device__ __forceinline__ u16 f2bf(float f){
    unsigned u = __float_as_uint(f);
    return (u16)((u + 0x7fffu + ((u>>16)&1u)) >> 16);
}
__device__ __forceinline__ float bf2f(unsigned u){
    return __uint_as_float(u << 16);
}

union U16x8 { u16 u[8]; float4 f4; };
union U16x4 { u16 u[4]; uint2 v2; };

// ---------------------------------------------------------------------------
// f32 -> bf16 elementwise convert (vectorized x4)
// ---------------------------------------------------------------------------
__global__ __launch_bounds__(256) void cvt_bf16_kernel(
    const float* __restrict__ src, u16* __restrict__ dst, int n4)
{
    int i = blockIdx.x * 256 + threadIdx.x;
    if (i < n4) {
        float4 v = ((const float4*)src)[i];
        U16x4 o;
        o.u[0] = f2bf(v.x); o.u[1] = f2bf(v.y); o.u[2] = f2bf(v.z); o.u[3] = f2bf(v.w);
        *(uint2*)(dst + (size_t)i*4) = o.v2;
    }
}

// ---------------------------------------------------------------------------
// W[768][768] f32 -> Wt[n][k] bf16 (transpose + convert). grid (12,12), 256thr
// ---------------------------------------------------------------------------
__global__ __launch_bounds__(256) void transcvt_kernel(
    const float* __restrict__ W, u16* __restrict__ Wt)
{
    __shared__ float T[64][65];
    const int t = threadIdx.x;
    const int k0 = blockIdx.y * 64, n0 = blockIdx.x * 64;
    #pragma unroll
    for (int i = 0; i < 4; ++i) {
        int idx = t + 256*i;
        int r = idx >> 4, c4 = idx & 15;
        float4 v = *(const float4*)(W + (size_t)(k0 + r)*EMB + n0 + c4*4);
        T[r][c4*4+0] = v.x; T[r][c4*4+1] = v.y; T[r][c4*4+2] = v.z; T[r][c4*4+3] = v.w;
    }
    __syncthreads();
    #pragma unroll
    for (int i = 0; i < 2; ++i) {
        int idx = t + 256*i;
        int n = idx >> 3, c = idx & 7;
        U16x8 o;
        #pragma unroll
        for (int e = 0; e < 8; ++e) o.u[e] = f2bf(T[c*8+e][n]);
        *(float4*)(Wt + (size_t)(n0 + n)*EMB + k0 + c*8) = o.f4;
    }
}

// ---------------------------------------------------------------------------
// QKV projection MFMA (unchanged)
// ---------------------------------------------------------------------------
__global__ __launch_bounds__(256) void qkv_mfma_kernel(
    const u16* __restrict__ hsb,
    const u16* __restrict__ WqT, const float* __restrict__ bq,
    const u16* __restrict__ WkT, const float* __restrict__ bk,
    const u16* __restrict__ WvT, const float* __restrict__ bv,
    u16* __restrict__ qo, u16* __restrict__ ko, u16* __restrict__ vo)
{
    const u16* Wt; const float* bias; u16* out;
    if (blockIdx.z == 0)      { Wt = WqT; bias = bq; out = qo; }
    else if (blockIdx.z == 1) { Wt = WkT; bias = bk; out = ko; }
    else                      { Wt = WvT; bias = bv; out = vo; }

    __shared__ __align__(16) u16 As[64*64];
    __shared__ __align__(16) u16 Bs[64*64];
    const int tid = threadIdx.x;
    const int w = tid >> 6, lane = tid & 63, lh = lane & 15, g = lane >> 4;
    const int wm = w >> 1, wn = w & 1;
    const int row0 = blockIdx.y * 64, col0 = blockIdx.x * 64;

    f32x4 acc[2][2];
    #pragma unroll
    for (int i = 0; i < 2; ++i)
        #pragma unroll
        for (int j = 0; j < 2; ++j) acc[i][j] = (f32x4){0.f,0.f,0.f,0.f};

    for (int k0 = 0; k0 < EMB; k0 += 64) {
        __syncthreads();
        #pragma unroll
        for (int i = 0; i < 2; ++i) {
            int idx = tid + 256*i;
            int r = idx >> 3, c = idx & 7;
            float4 a4 = *(const float4*)(hsb + (size_t)(row0 + r)*EMB + k0 + c*8);
            *(float4*)(As + ((size_t)r*8 + (c ^ (r & 7)))*8) = a4;
            float4 b4 = *(const float4*)(Wt + (size_t)(col0 + r)*EMB + k0 + c*8);
            *(float4*)(Bs + ((size_t)r*8 + (c ^ (r & 7)))*8) = b4;
        }
        __syncthreads();
        bf16x8 af[2][2], bfr[2][2];
        #pragma unroll
        for (int mt = 0; mt < 2; ++mt)
            #pragma unroll
            for (int kk = 0; kk < 2; ++kk) {
                int r = wm*32 + mt*16 + lh;
                af[mt][kk] = *(const bf16x8*)(As + ((size_t)r*8 + ((kk*4+g) ^ (lh & 7)))*8);
            }
        #pragma unroll
        for (int nt = 0; nt < 2; ++nt)
            #pragma unroll
            for (int kk = 0; kk < 2; ++kk) {
                int r = wn*32 + nt*16 + lh;
                bfr[nt][kk] = *(const bf16x8*)(Bs + ((size_t)r*8 + ((kk*4+g) ^ (lh & 7)))*8);
            }
        #pragma unroll
        for (int mt = 0; mt < 2; ++mt)
            #pragma unroll
            for (int nt = 0; nt < 2; ++nt)
                #pragma unroll
                for (int kk = 0; kk < 2; ++kk)
                    acc[mt][nt] = MFMA16(af[mt][kk], bfr[nt][kk], acc[mt][nt]);
    }

    #pragma unroll
    for (int mt = 0; mt < 2; ++mt)
        #pragma unroll
        for (int nt = 0; nt < 2; ++nt)
            #pragma unroll
            for (int r = 0; r < 4; ++r) {
                int tt = row0 + wm*32 + mt*16 + g*4 + r;
                int o  = col0 + wn*32 + nt*16 + lh;
                float val = acc[mt][nt][r] + bias[o];
                int b = tt >> 11, s = tt & (S_LEN - 1);
                int h = o / HD, d = o - h*HD;
                out[((size_t)(b*NH + h)*S_LEN + s)*HD + d] = f2bf(val);
            }
}

// ---------------------------------------------------------------------------
// V transpose: vb[B,H,S,D] bf16 -> vt[B,H,D,S] bf16 (unchanged)
// ---------------------------------------------------------------------------
__global__ __launch_bounds__(256) void vtrans_kernel(
    const u16* __restrict__ vb, u16* __restrict__ vt)
{
    const int bh = blockIdx.y;
    const int s0 = blockIdx.x * 64;
    __shared__ __align__(16) u16 T[64*96];
    const int t = threadIdx.x;
    #pragma unroll
    for (int i = 0; i < 3; ++i) {
        int idx = t + 256*i;
        int s = idx / 12, c = idx % 12;
        float4 v = *(const float4*)(vb + ((size_t)bh*S_LEN + s0 + s)*HD + c*8);
        *(float4*)(T + ((size_t)s*12 + c)*8) = v;
    }
    __syncthreads();
    #pragma unroll
    for (int i = 0; i < 3; ++i) {
        int idx = t + 256*i;
        int d = idx >> 3, c = idx & 7;
        U16x8 o;
        #pragma unroll
        for (int e = 0; e < 8; ++e) o.u[e] = T[(size_t)(c*8+e)*HD + d];
        *(float4*)(vt + ((size_t)bh*HD + d)*S_LEN + s0 + c*8) = o.f4;
    }
}

// ---------------------------------------------------------------------------
// FUSED attention: scores (no-max softmax) + probs write + PV, one kernel.
// QBLK=32 q-rows/block, 512 threads (8 waves), grid (64, 16).
// u stripe (32 x 2048 bf16 = 128 KB) lives entirely in LDS between phases —
// kills the 268 MB ubuf HBM round-trip of the two-pass version.
// LDS: Us 128K + Ks/Vs 12K + Sf 8.5K + mL = 152 KB (gfx950 limit 160 KB).
// ---------------------------------------------------------------------------
__global__ __launch_bounds__(512) void fused_attn_kernel(
    const u16* __restrict__ qbf, const u16* __restrict__ kbf,
    const u16* __restrict__ vt,
    const float* __restrict__ dist, const float* __restrict__ ang,
    const float* __restrict__ mask,
    const float* __restrict__ pdw, const float* __restrict__ pdb,
    const float* __restrict__ paw, const float* __restrict__ pab,
    float* __restrict__ probs, u16* __restrict__ ctxb)
{
    const int bh = blockIdx.y, b = bh >> 3, h = bh & 7;
    const int q0 = blockIdx.x * 32;
    const int tid = threadIdx.x;
    const int lane = tid & 63, w = tid >> 6, lh = lane & 15, g = lane >> 4;
    const int rt = w >> 2;              // row-tile (0,1) for QK and PV
    const int ct = w & 3;               // col-tile for QK; d-tile base for PV

    __shared__ __align__(16) u16 Us[32*2048];    // u stripe, per-kt swizzled subtiles
    __shared__ __align__(16) u16 Ks[64*96];      // K tile (phase A) / V tile (phase B)
    __shared__ __align__(16) float Sf[32*68];    // acc staging; Q staged here first
    __shared__ float mL[32];

    // ---- stage Q (as u16, into Sf region) and read fragments ----
    u16* Qtmp = (u16*)Sf;
    if (tid < 384) {
        int r = tid / 12, c = tid % 12;
        float4 v = *(const float4*)(qbf + ((size_t)bh*S_LEN + q0 + r)*HD + c*8);
        *(float4*)(Qtmp + ((size_t)r*12 + (c ^ ((r >> 1) & 3)))*8) = v;
    }
    __syncthreads();
    bf16x8 qf[3];
    #pragma unroll
    for (int kk = 0; kk < 3; ++kk) {
        int r = rt*16 + lh;
        qf[kk] = *(const bf16x8*)(Qtmp + ((size_t)r*12 + ((kk*4+g) ^ ((r >> 1) & 3)))*8);
    }
    __syncthreads();   // protect Qtmp region before Sf f32 reuse

    const float DW = *pdw, AW = *paw, CB = *pdb + *pab;
    const int trow = tid >> 4;          // 0..31 (epilogue row)
    const int c4   = tid & 15;          // float4 col chunk
    const size_t drow = ((size_t)b*S_LEN + q0 + trow)*S_LEN;
    // swizzled LDS u offset for this thread's 4 cols (uint2)
    const int uoff = (trow*8 + ((c4 >> 1) ^ (trow & 7)))*8 + (c4 & 1)*4;

    float lpart = 0.f;

    // ================= Phase A: QK^T -> u = exp(s) into LDS =================
    for (int kt = 0; kt < 32; ++kt) {
        int coff = kt*64 + c4*4;
        // bias/mask loads for this kt (consumed in epilogue after barrier 2)
        float4 d4 = *(const float4*)(dist + drow + coff);
        float4 g4 = *(const float4*)(ang  + drow + coff);
        float4 m4 = *(const float4*)(mask + b*S_LEN + coff);
        // stage K tile 64x96 (768 chunks over 512 threads)
        {
            int r = tid / 12, c = tid - r*12;
            float4 v = *(const float4*)(kbf + ((size_t)bh*S_LEN + kt*64 + r)*HD + c*8);
            *(float4*)(Ks + ((size_t)r*12 + (c ^ ((r >> 1) & 3)))*8) = v;
            if (tid < 256) {
                int idx = tid + 512;
                int r2 = idx / 12, c2 = idx - r2*12;
                float4 v2 = *(const float4*)(kbf + ((size_t)bh*S_LEN + kt*64 + r2)*HD + c2*8);
                *(float4*)(Ks + ((size_t)r2*12 + (c2 ^ ((r2 >> 1) & 3)))*8) = v2;
            }
        }
        __syncthreads();

        f32x4 acc = (f32x4){0.f,0.f,0.f,0.f};
        #pragma unroll
        for (int kk = 0; kk < 3; ++kk) {
            int kr = ct*16 + lh;
            bf16x8 kf = *(const bf16x8*)(Ks + ((size_t)kr*12 + ((kk*4+g) ^ ((kr >> 1) & 3)))*8);
            acc = MFMA16(qf[kk], kf, acc);
        }
        #pragma unroll
        for (int r = 0; r < 4; ++r)
            Sf[(rt*16 + g*4 + r)*68 + ct*16 + lh] = acc[r];
        __syncthreads();

        // epilogue: one row x 4 cols per thread
        float4 s4 = *(const float4*)&Sf[trow*68 + c4*4];
        float e0 = __expf(s4.x*RSQRT_D + DW*d4.x + AW*g4.x + CB + (1.f - m4.x) * -10000.f);
        float e1 = __expf(s4.y*RSQRT_D + DW*d4.y + AW*g4.y + CB + (1.f - m4.y) * -10000.f);
        float e2 = __expf(s4.z*RSQRT_D + DW*d4.z + AW*g4.z + CB + (1.f - m4.z) * -10000.f);
        float e3 = __expf(s4.w*RSQRT_D + DW*d4.w + AW*g4.w + CB + (1.f - m4.w) * -10000.f);
        lpart += (e0 + e1) + (e2 + e3);
        U16x4 uk;
        uk.u[0] = f2bf(e0); uk.u[1] = f2bf(e1); uk.u[2] = f2bf(e2); uk.u[3] = f2bf(e3);
        *(uint2*)(Us + (size_t)kt*2048 + uoff) = uk.v2;
        // no extra barrier: next Ks stage is safe (all MFMA reads done pre-B2;
        // epilogue touches only Sf/Us; B1 of next iter orders Sf reuse).
    }

    // row-sum reduce across the 16 threads of each row (same wave)
    #pragma unroll
    for (int off = 1; off <= 8; off <<= 1) lpart += __shfl_xor(lpart, off);
    if (c4 == 0) mL[trow] = 1.0f / lpart;
    __syncthreads();

    // ================= Phase B: probs = u*invl, ctx = (u @ V)*invl ==========
    const float invl_row = mL[trow];
    const int dt1 = ct;                 // first d-tile
    const bool two = (ct < 2);          // waves 0,1 (per rt) take d-tiles 4,5
    const int dt2 = ct + 4;
    f32x4 accA = (f32x4){0.f,0.f,0.f,0.f};
    f32x4 accB = (f32x4){0.f,0.f,0.f,0.f};

    for (int kt = 0; kt < 32; ++kt) {
        // stage V tile 96x64 (768 chunks) into Ks region
        {
            int vr = tid >> 3, c = tid & 7;
            float4 v4 = *(const float4*)(vt + ((size_t)bh*HD + vr)*S_LEN + kt*64 + c*8);
            *(float4*)(Ks + ((size_t)vr*8 + (c ^ (vr & 7)))*8) = v4;
            if (tid < 256) {
                int idx = tid + 512;
                int vr2 = idx >> 3, c2 = idx & 7;
                float4 v42 = *(const float4*)(vt + ((size_t)bh*HD + vr2)*S_LEN + kt*64 + c2*8);
                *(float4*)(Ks + ((size_t)vr2*8 + (c2 ^ (vr2 & 7)))*8) = v42;
            }
        }
        // probs write straight from LDS u
        {
            uint2 uu = *(const uint2*)(Us + (size_t)kt*2048 + uoff);
            float4 p;
            p.x = bf2f(uu.x & 0xffffu)*invl_row; p.y = bf2f(uu.x >> 16)*invl_row;
            p.z = bf2f(uu.y & 0xffffu)*invl_row; p.w = bf2f(uu.y >> 16)*invl_row;
            *(float4*)(probs + ((size_t)bh*S_LEN + q0 + trow)*S_LEN + kt*64 + c4*4) = p;
        }
        __syncthreads();

        int prow = rt*16 + lh;
        bf16x8 pa[2];
        #pragma unroll
        for (int kk = 0; kk < 2; ++kk)
            pa[kk] = *(const bf16x8*)(Us + (size_t)kt*2048 + ((size_t)prow*8 + ((kk*4+g) ^ (prow & 7)))*8);
        #pragma unroll
        for (int kk = 0; kk < 2; ++kk) {
            int vr = dt1*16 + lh;
            bf16x8 vf = *(const bf16x8*)(Ks + ((size_t)vr*8 + ((kk*4+g) ^ (vr & 7)))*8);
            accA = MFMA16(pa[kk], vf, accA);
        }
        if (two) {
            #pragma unroll
            for (int kk = 0; kk < 2; ++kk) {
                int vr = dt2*16 + lh;
                bf16x8 vf = *(const bf16x8*)(Ks + ((size_t)vr*8 + ((kk*4+g) ^ (vr & 7)))*8);
                accB = MFMA16(pa[kk], vf, accB);
            }
        }
        __syncthreads();
    }

    // ctx write (scaled by invl per row)
    float ils[4];
    #pragma unroll
    for (int r = 0; r < 4; ++r) ils[r] = mL[rt*16 + g*4 + r];
    #pragma unroll
    for (int r = 0; r < 4; ++r) {
        int qrow = q0 + rt*16 + g*4 + r;
        ctxb[((size_t)(b*S_LEN + qrow))*EMB + h*HD + dt1*16 + lh] = f2bf(accA[r] * ils[r]);
        if (two)
            ctxb[((size_t)(b*S_LEN + qrow))*EMB + h*HD + dt2*16 + lh] = f2bf(accB[r] * ils[r]);
    }
}

// ---------------------------------------------------------------------------
// Output proj MFMA (unchanged)
// ---------------------------------------------------------------------------
__global__ __launch_bounds__(256) void out_mfma_kernel(
    const u16* __restrict__ ctxb, const u16* __restrict__ WoT,
    const float* __restrict__ bo, const float* __restrict__ hs,
    float* __restrict__ res)
{
    __shared__ __align__(16) u16 As[64*64];
    __shared__ __align__(16) u16 Bs[64*64];
    const int tid = threadIdx.x;
    const int w = tid >> 6, lane = tid & 63, lh = lane & 15, g = lane >> 4;
    const int wm = w >> 1, wn = w & 1;
    const int row0 = blockIdx.y * 64, col0 = blockIdx.x * 64;

    f32x4 acc[2][2];
    #pragma unroll
    for (int i = 0; i < 2; ++i)
        #pragma unroll
        for (int j = 0; j < 2; ++j) acc[i][j] = (f32x4){0.f,0.f,0.f,0.f};

    for (int k0 = 0; k0 < EMB; k0 += 64) {
        __syncthreads();
        #pragma unroll
        for (int i = 0; i < 2; ++i) {
            int idx = tid + 256*i;
            int r = idx >> 3, c = idx & 7;
            float4 a4 = *(const float4*)(ctxb + (size_t)(row0 + r)*EMB + k0 + c*8);
            *(float4*)(As + ((size_t)r*8 + (c ^ (r & 7)))*8) = a4;
            float4 b4 = *(const float4*)(WoT + (size_t)(col0 + r)*EMB + k0 + c*8);
            *(float4*)(Bs + ((size_t)r*8 + (c ^ (r & 7)))*8) = b4;
        }
        __syncthreads();
        bf16x8 af[2][2], bfr[2][2];
        #pragma unroll
        for (int mt = 0; mt < 2; ++mt)
            #pragma unroll
            for (int kk = 0; kk < 2; ++kk) {
                int r = wm*32 + mt*16 + lh;
                af[mt][kk] = *(const bf16x8*)(As + ((size_t)r*8 + ((kk*4+g) ^ (lh & 7)))*8);
            }
        #pragma unroll
        for (int nt = 0; nt < 2; ++nt)
            #pragma unroll
            for (int kk = 0; kk < 2; ++kk) {
                int r = wn*32 + nt*16 + lh;
                bfr[nt][kk] = *(const bf16x8*)(Bs + ((size_t)r*8 + ((kk*4+g) ^ (lh & 7)))*8);
            }
        #pragma unroll
        for (int mt = 0; mt < 2; ++mt)
            #pragma unroll
            for (int nt = 0; nt < 2; ++nt)
                #pragma unroll
                for (int kk = 0; kk < 2; ++kk)
                    acc[mt][nt] = MFMA16(af[mt][kk], bfr[nt][kk], acc[mt][nt]);
    }

    #pragma unroll
    for (int mt = 0; mt < 2; ++mt)
        #pragma unroll
        for (int nt = 0; nt < 2; ++nt)
            #pragma unroll
            for (int r = 0; r < 4; ++r) {
                int tt = row0 + wm*32 + mt*16 + g*4 + r;
                int o  = col0 + wn*32 + nt*16 + lh;
                res[(size_t)tt*EMB + o] = acc[mt][nt][r] + bo[o] + hs[(size_t)tt*EMB + o];
            }
}

// ---------------------------------------------------------------------------
// LayerNorm in place over last dim 768. grid NTOK, block 256.
// ---------------------------------------------------------------------------
__device__ __forceinline__ float block_sum256(float v, float* red) {
    #pragma unroll
    for (int off = 32; off > 0; off >>= 1) v += __shfl_down(v, off);
    int lane = threadIdx.x & 63, w = threadIdx.x >> 6;
    __syncthreads();
    if (lane == 0) red[w] = v;
    __syncthreads();
    return red[0] + red[1] + red[2] + red[3];
}

__global__ __launch_bounds__(256) void ln_kernel(
    float* __restrict__ res, const float* __restrict__ gamma, const float* __restrict__ beta)
{
    const int t = blockIdx.x;
    float* row = res + (size_t)t * EMB;
    const int tid = threadIdx.x;
    __shared__ float red[4];

    float x0 = row[tid], x1 = row[tid + 256], x2 = row[tid + 512];
    float s = block_sum256(x0 + x1 + x2, red);
    float mu = s * (1.0f / (float)EMB);
    float d0 = x0 - mu, d1 = x1 - mu, d2 = x2 - mu;
    float sq = block_sum256(d0*d0 + d1*d1 + d2*d2, red);
    float var = sq * (1.0f / (float)EMB);
    float scale = rsqrtf(var + 1e-5f);

    row[tid]       = d0 * scale * gamma[tid]       + beta[tid];
    row[tid + 256] = d1 * scale * gamma[tid + 256] + beta[tid + 256];
    row[tid + 512] = d2 * scale * gamma[tid + 512] + beta[tid + 512];
}

// ---------------------------------------------------------------------------
extern "C" void kernel_launch(void* const* d_in, const int* in_sizes, int n_in,
                              void* d_out, int out_size, void* d_ws, size_t ws_size,
                              hipStream_t stream)
{
    (void)in_sizes; (void)n_in; (void)out_size; (void)ws_size;

    const float* hs   = (const float*)d_in[0];
    const float* dist = (const float*)d_in[1];
    const float* ang  = (const float*)d_in[2];
    const float* mask = (const float*)d_in[3];
    const float* Wq = (const float*)d_in[4];  const float* bq = (const float*)d_in[5];
    const float* Wk = (const float*)d_in[6];  const float* bk = (const float*)d_in[7];
    const float* Wv = (const float*)d_in[8];  const float* bv = (const float*)d_in[9];
    const float* dw = (const float*)d_in[10]; const float* db = (const float*)d_in[11];
    const float* aw = (const float*)d_in[12]; const float* ab = (const float*)d_in[13];
    const float* Wo = (const float*)d_in[14]; const float* bo = (const float*)d_in[15];
    const float* gamma = (const float*)d_in[16]; const float* beta = (const float*)d_in[17];

    float* out   = (float*)d_out;                      // [B,S,E]
    float* probs = out + (size_t)NTOK * EMB;           // [B,H,S,S]

    u16* hsb = (u16*)d_ws;
    u16* WqT = hsb + (size_t)NTOK*EMB;
    u16* WkT = WqT + (size_t)EMB*EMB;
    u16* WvT = WkT + (size_t)EMB*EMB;
    u16* WoT = WvT + (size_t)EMB*EMB;
    u16* qb  = WoT + (size_t)EMB*EMB;
    u16* kb  = qb + (size_t)NTOK*EMB;
    u16* vb  = kb + (size_t)NTOK*EMB;
    u16* vtb = vb + (size_t)NTOK*EMB;
    u16* ctxb = qb;                                    // reuse q region after attn

    cvt_bf16_kernel<<<dim3(NTOK*EMB/4/256), dim3(256), 0, stream>>>(hs, hsb, NTOK*EMB/4);
    transcvt_kernel<<<dim3(12,12), dim3(256), 0, stream>>>(Wq, WqT);
    transcvt_kernel<<<dim3(12,12), dim3(256), 0, stream>>>(Wk, WkT);
    transcvt_kernel<<<dim3(12,12), dim3(256), 0, stream>>>(Wv, WvT);
    transcvt_kernel<<<dim3(12,12), dim3(256), 0, stream>>>(Wo, WoT);

    qkv_mfma_kernel<<<dim3(EMB/64, NTOK/64, 3), dim3(256), 0, stream>>>(
        hsb, WqT, bq, WkT, bk, WvT, bv, qb, kb, vb);

    vtrans_kernel<<<dim3(S_LEN/64, BATCH*NH), dim3(256), 0, stream>>>(vb, vtb);

    fused_attn_kernel<<<dim3(S_LEN/32, BATCH*NH), dim3(512), 0, stream>>>(
        qb, kb, vtb, dist, ang, mask, dw, db, aw, ab, probs, ctxb);

    out_mfma_kernel<<<dim3(EMB/64, NTOK/64), dim3(256), 0, stream>>>(
        ctxb, WoT, bo, hs, out);

    ln_kernel<<<dim3(NTOK), dim3(256), 0, stream>>>(out, gamma, beta);
}

// Round 10
// 267.289 us; speedup vs baseline: 1.4721x; 1.2064x over previous
//
#include <hip/hip_runtime.h>
#include <math.h>

#define S_LEN 2048
#define BATCH 2
#define EMB 768
#define NH 8
#define HD 96
#define NTOK (BATCH*S_LEN)
#define RSQRT_D 0.10206207261596575f   // 1/sqrt(96)

typedef unsigned short u16;
typedef __attribute__((ext_vector_type(8))) short bf16x8;
typedef __attribute__((ext_vector_type(4))) float f32x4;

#define MFMA16(a,b,c) __builtin_amdgcn_mfma_f32_16x16x32_bf16(a,b,c,0,0,0)

__device__ __forceinline__ u16 f2bf(float f){
    unsigned u = __float_as_uint(f);
    return (u16)((u + 0x7fffu + ((u>>16)&1u)) >> 16);
}
__device__ __forceinline__ float bf2f(unsigned u){
    return __uint_as_float(u << 16);
}

union U16x8 { u16 u[8]; float4 f4; };
union U16x4 { u16 u[4]; uint2 v2; };

// ---------------------------------------------------------------------------
// f32 -> bf16 elementwise convert (vectorized x4)
// ---------------------------------------------------------------------------
__global__ __launch_bounds__(256) void cvt_bf16_kernel(
    const float* __restrict__ src, u16* __restrict__ dst, int n4)
{
    int i = blockIdx.x * 256 + threadIdx.x;
    if (i < n4) {
        float4 v = ((const float4*)src)[i];
        U16x4 o;
        o.u[0] = f2bf(v.x); o.u[1] = f2bf(v.y); o.u[2] = f2bf(v.z); o.u[3] = f2bf(v.w);
        *(uint2*)(dst + (size_t)i*4) = o.v2;
    }
}

// ---------------------------------------------------------------------------
// W[768][768] f32 -> Wt[n][k] bf16 (transpose + convert). grid (12,12), 256thr
// ---------------------------------------------------------------------------
__global__ __launch_bounds__(256) void transcvt_kernel(
    const float* __restrict__ W, u16* __restrict__ Wt)
{
    __shared__ float T[64][65];
    const int t = threadIdx.x;
    const int k0 = blockIdx.y * 64, n0 = blockIdx.x * 64;
    #pragma unroll
    for (int i = 0; i < 4; ++i) {
        int idx = t + 256*i;
        int r = idx >> 4, c4 = idx & 15;
        float4 v = *(const float4*)(W + (size_t)(k0 + r)*EMB + n0 + c4*4);
        T[r][c4*4+0] = v.x; T[r][c4*4+1] = v.y; T[r][c4*4+2] = v.z; T[r][c4*4+3] = v.w;
    }
    __syncthreads();
    #pragma unroll
    for (int i = 0; i < 2; ++i) {
        int idx = t + 256*i;
        int n = idx >> 3, c = idx & 7;
        U16x8 o;
        #pragma unroll
        for (int e = 0; e < 8; ++e) o.u[e] = f2bf(T[c*8+e][n]);
        *(float4*)(Wt + (size_t)(n0 + n)*EMB + k0 + c*8) = o.f4;
    }
}

// ---------------------------------------------------------------------------
// QKV projection MFMA (unchanged)
// ---------------------------------------------------------------------------
__global__ __launch_bounds__(256) void qkv_mfma_kernel(
    const u16* __restrict__ hsb,
    const u16* __restrict__ WqT, const float* __restrict__ bq,
    const u16* __restrict__ WkT, const float* __restrict__ bk,
    const u16* __restrict__ WvT, const float* __restrict__ bv,
    u16* __restrict__ qo, u16* __restrict__ ko, u16* __restrict__ vo)
{
    const u16* Wt; const float* bias; u16* out;
    if (blockIdx.z == 0)      { Wt = WqT; bias = bq; out = qo; }
    else if (blockIdx.z == 1) { Wt = WkT; bias = bk; out = ko; }
    else                      { Wt = WvT; bias = bv; out = vo; }

    __shared__ __align__(16) u16 As[64*64];
    __shared__ __align__(16) u16 Bs[64*64];
    const int tid = threadIdx.x;
    const int w = tid >> 6, lane = tid & 63, lh = lane & 15, g = lane >> 4;
    const int wm = w >> 1, wn = w & 1;
    const int row0 = blockIdx.y * 64, col0 = blockIdx.x * 64;

    f32x4 acc[2][2];
    #pragma unroll
    for (int i = 0; i < 2; ++i)
        #pragma unroll
        for (int j = 0; j < 2; ++j) acc[i][j] = (f32x4){0.f,0.f,0.f,0.f};

    for (int k0 = 0; k0 < EMB; k0 += 64) {
        __syncthreads();
        #pragma unroll
        for (int i = 0; i < 2; ++i) {
            int idx = tid + 256*i;
            int r = idx >> 3, c = idx & 7;
            float4 a4 = *(const float4*)(hsb + (size_t)(row0 + r)*EMB + k0 + c*8);
            *(float4*)(As + ((size_t)r*8 + (c ^ (r & 7)))*8) = a4;
            float4 b4 = *(const float4*)(Wt + (size_t)(col0 + r)*EMB + k0 + c*8);
            *(float4*)(Bs + ((size_t)r*8 + (c ^ (r & 7)))*8) = b4;
        }
        __syncthreads();
        bf16x8 af[2][2], bfr[2][2];
        #pragma unroll
        for (int mt = 0; mt < 2; ++mt)
            #pragma unroll
            for (int kk = 0; kk < 2; ++kk) {
                int r = wm*32 + mt*16 + lh;
                af[mt][kk] = *(const bf16x8*)(As + ((size_t)r*8 + ((kk*4+g) ^ (lh & 7)))*8);
            }
        #pragma unroll
        for (int nt = 0; nt < 2; ++nt)
            #pragma unroll
            for (int kk = 0; kk < 2; ++kk) {
                int r = wn*32 + nt*16 + lh;
                bfr[nt][kk] = *(const bf16x8*)(Bs + ((size_t)r*8 + ((kk*4+g) ^ (lh & 7)))*8);
            }
        #pragma unroll
        for (int mt = 0; mt < 2; ++mt)
            #pragma unroll
            for (int nt = 0; nt < 2; ++nt)
                #pragma unroll
                for (int kk = 0; kk < 2; ++kk)
                    acc[mt][nt] = MFMA16(af[mt][kk], bfr[nt][kk], acc[mt][nt]);
    }

    #pragma unroll
    for (int mt = 0; mt < 2; ++mt)
        #pragma unroll
        for (int nt = 0; nt < 2; ++nt)
            #pragma unroll
            for (int r = 0; r < 4; ++r) {
                int tt = row0 + wm*32 + mt*16 + g*4 + r;
                int o  = col0 + wn*32 + nt*16 + lh;
                float val = acc[mt][nt][r] + bias[o];
                int b = tt >> 11, s = tt & (S_LEN - 1);
                int h = o / HD, d = o - h*HD;
                out[((size_t)(b*NH + h)*S_LEN + s)*HD + d] = f2bf(val);
            }
}

// ---------------------------------------------------------------------------
// V transpose: vb[B,H,S,D] bf16 -> vt[B,H,D,S] bf16 (unchanged)
// ---------------------------------------------------------------------------
__global__ __launch_bounds__(256) void vtrans_kernel(
    const u16* __restrict__ vb, u16* __restrict__ vt)
{
    const int bh = blockIdx.y;
    const int s0 = blockIdx.x * 64;
    __shared__ __align__(16) u16 T[64*96];
    const int t = threadIdx.x;
    #pragma unroll
    for (int i = 0; i < 3; ++i) {
        int idx = t + 256*i;
        int s = idx / 12, c = idx % 12;
        float4 v = *(const float4*)(vb + ((size_t)bh*S_LEN + s0 + s)*HD + c*8);
        *(float4*)(T + ((size_t)s*12 + c)*8) = v;
    }
    __syncthreads();
    #pragma unroll
    for (int i = 0; i < 3; ++i) {
        int idx = t + 256*i;
        int d = idx >> 3, c = idx & 7;
        U16x8 o;
        #pragma unroll
        for (int e = 0; e < 8; ++e) o.u[e] = T[(size_t)(c*8+e)*HD + d];
        *(float4*)(vt + ((size_t)bh*HD + d)*S_LEN + s0 + c*8) = o.f4;
    }
}

// ---------------------------------------------------------------------------
// FUSED attention (pipelined): scores + probs + PV, one kernel.
// QBLK=32, 512 threads (8 waves), grid (64,16). u stripe in LDS (128 KB).
// T14 pipeline: K/V tile kt+1 loaded into REGS during MFMA(kt); ds_write
// after the post-MFMA barrier — HBM latency hides under compute.
// ---------------------------------------------------------------------------
__global__ __launch_bounds__(512) void fused_attn_kernel(
    const u16* __restrict__ qbf, const u16* __restrict__ kbf,
    const u16* __restrict__ vt,
    const float* __restrict__ dist, const float* __restrict__ ang,
    const float* __restrict__ mask,
    const float* __restrict__ pdw, const float* __restrict__ pdb,
    const float* __restrict__ paw, const float* __restrict__ pab,
    float* __restrict__ probs, u16* __restrict__ ctxb)
{
    const int bh = blockIdx.y, b = bh >> 3, h = bh & 7;
    const int q0 = blockIdx.x * 32;
    const int tid = threadIdx.x;
    const int lane = tid & 63, w = tid >> 6, lh = lane & 15, g = lane >> 4;
    const int rt = w >> 2;              // row-tile (0,1)
    const int ct = w & 3;               // col-tile (QK) / d-tile base (PV)

    __shared__ __align__(16) u16 Us[32*2048];    // u stripe (128 KB)
    __shared__ __align__(16) u16 Ks[64*96];      // K tile (A) / V tile (B)
    __shared__ __align__(16) float Sf[32*68];    // acc staging; Q staged first
    __shared__ float mL[32];

    // staging index helpers
    const int kr_s = tid / 12, kc_s = tid - (tid / 12) * 12;        // K chunks
    const int kr2_s = (tid + 512) / 12, kc2_s = (tid + 512) - ((tid + 512) / 12) * 12;
    const int vr_s = tid >> 3, vc_s = tid & 7;                      // V chunks
    const int vr2_s = (tid + 512) >> 3, vc2_s = (tid + 512) & 7;

    // ---- prologue: stage Q (into Sf region) and K tile 0 ----
    u16* Qtmp = (u16*)Sf;
    if (tid < 384) {
        int r = tid / 12, c = tid % 12;
        float4 v = *(const float4*)(qbf + ((size_t)bh*S_LEN + q0 + r)*HD + c*8);
        *(float4*)(Qtmp + ((size_t)r*12 + (c ^ ((r >> 1) & 3)))*8) = v;
    }
    {
        float4 v = *(const float4*)(kbf + ((size_t)bh*S_LEN + kr_s)*HD + kc_s*8);
        *(float4*)(Ks + ((size_t)kr_s*12 + (kc_s ^ ((kr_s >> 1) & 3)))*8) = v;
        if (tid < 256) {
            float4 v2 = *(const float4*)(kbf + ((size_t)bh*S_LEN + kr2_s)*HD + kc2_s*8);
            *(float4*)(Ks + ((size_t)kr2_s*12 + (kc2_s ^ ((kr2_s >> 1) & 3)))*8) = v2;
        }
    }
    __syncthreads();
    bf16x8 qf[3];
    #pragma unroll
    for (int kk = 0; kk < 3; ++kk) {
        int r = rt*16 + lh;
        qf[kk] = *(const bf16x8*)(Qtmp + ((size_t)r*12 + ((kk*4+g) ^ ((r >> 1) & 3)))*8);
    }
    __syncthreads();   // protect Qtmp region before Sf f32 reuse

    const float DW = *pdw, AW = *paw, CB = *pdb + *pab;
    const int trow = tid >> 4;          // 0..31 (epilogue row)
    const int c4   = tid & 15;          // float4 col chunk
    const size_t drow = ((size_t)b*S_LEN + q0 + trow)*S_LEN;
    const int uoff = (trow*8 + ((c4 >> 1) ^ (trow & 7)))*8 + (c4 & 1)*4;

    float lpart = 0.f;

    // ================= Phase A: QK^T -> u = exp(s) into LDS =================
    for (int kt = 0; kt < 32; ++kt) {
        int coff = kt*64 + c4*4;
        // issue next-K reg loads (consumed post-barrier; hides under MFMA)
        float4 kreg0, kreg1;
        if (kt < 31) {
            kreg0 = *(const float4*)(kbf + ((size_t)bh*S_LEN + (kt+1)*64 + kr_s)*HD + kc_s*8);
            if (tid < 256)
                kreg1 = *(const float4*)(kbf + ((size_t)bh*S_LEN + (kt+1)*64 + kr2_s)*HD + kc2_s*8);
        }
        // bias/mask loads for this kt (consumed in epilogue)
        float4 d4 = *(const float4*)(dist + drow + coff);
        float4 g4 = *(const float4*)(ang  + drow + coff);
        float4 m4 = *(const float4*)(mask + b*S_LEN + coff);

        // MFMA over current Ks
        f32x4 acc = (f32x4){0.f,0.f,0.f,0.f};
        #pragma unroll
        for (int kk = 0; kk < 3; ++kk) {
            int kr = ct*16 + lh;
            bf16x8 kf = *(const bf16x8*)(Ks + ((size_t)kr*12 + ((kk*4+g) ^ ((kr >> 1) & 3)))*8);
            acc = MFMA16(qf[kk], kf, acc);
        }
        #pragma unroll
        for (int r = 0; r < 4; ++r)
            Sf[(rt*16 + g*4 + r)*68 + ct*16 + lh] = acc[r];
        __syncthreads();   // B2: Sf ready, all Ks reads done

        // epilogue: one row x 4 cols per thread
        float4 s4 = *(const float4*)&Sf[trow*68 + c4*4];
        float e0 = __expf(s4.x*RSQRT_D + DW*d4.x + AW*g4.x + CB + (1.f - m4.x) * -10000.f);
        float e1 = __expf(s4.y*RSQRT_D + DW*d4.y + AW*g4.y + CB + (1.f - m4.y) * -10000.f);
        float e2 = __expf(s4.z*RSQRT_D + DW*d4.z + AW*g4.z + CB + (1.f - m4.z) * -10000.f);
        float e3 = __expf(s4.w*RSQRT_D + DW*d4.w + AW*g4.w + CB + (1.f - m4.w) * -10000.f);
        lpart += (e0 + e1) + (e2 + e3);
        U16x4 uk;
        uk.u[0] = f2bf(e0); uk.u[1] = f2bf(e1); uk.u[2] = f2bf(e2); uk.u[3] = f2bf(e3);
        *(uint2*)(Us + (size_t)kt*2048 + uoff) = uk.v2;

        // ds_write next K tile (regs -> LDS; loads drained during MFMA+epi)
        if (kt < 31) {
            *(float4*)(Ks + ((size_t)kr_s*12 + (kc_s ^ ((kr_s >> 1) & 3)))*8) = kreg0;
            if (tid < 256)
                *(float4*)(Ks + ((size_t)kr2_s*12 + (kc2_s ^ ((kr2_s >> 1) & 3)))*8) = kreg1;
        }
        __syncthreads();   // B1: Ks(kt+1) ready
    }

    // row-sum reduce; stage V tile 0 into Ks region under the same barrier
    #pragma unroll
    for (int off = 1; off <= 8; off <<= 1) lpart += __shfl_xor(lpart, off);
    if (c4 == 0) mL[trow] = 1.0f / lpart;
    {
        float4 v4 = *(const float4*)(vt + ((size_t)bh*HD + vr_s)*S_LEN + vc_s*8);
        *(float4*)(Ks + ((size_t)vr_s*8 + (vc_s ^ (vr_s & 7)))*8) = v4;
        if (tid < 256) {
            float4 v42 = *(const float4*)(vt + ((size_t)bh*HD + vr2_s)*S_LEN + vc2_s*8);
            *(float4*)(Ks + ((size_t)vr2_s*8 + (vc2_s ^ (vr2_s & 7)))*8) = v42;
        }
    }
    __syncthreads();

    // ================= Phase B: probs = u*invl, ctx = (u @ V)*invl ==========
    const float invl_row = mL[trow];
    const int dt1 = ct;
    const bool two = (ct < 2);
    const int dt2 = ct + 4;
    f32x4 accA = (f32x4){0.f,0.f,0.f,0.f};
    f32x4 accB = (f32x4){0.f,0.f,0.f,0.f};

    for (int kt = 0; kt < 32; ++kt) {
        // issue next-V reg loads (hide under probs write + MFMA)
        float4 vreg0, vreg1;
        if (kt < 31) {
            vreg0 = *(const float4*)(vt + ((size_t)bh*HD + vr_s)*S_LEN + (kt+1)*64 + vc_s*8);
            if (tid < 256)
                vreg1 = *(const float4*)(vt + ((size_t)bh*HD + vr2_s)*S_LEN + (kt+1)*64 + vc2_s*8);
        }
        // probs write straight from LDS u
        {
            uint2 uu = *(const uint2*)(Us + (size_t)kt*2048 + uoff);
            float4 p;
            p.x = bf2f(uu.x & 0xffffu)*invl_row; p.y = bf2f(uu.x >> 16)*invl_row;
            p.z = bf2f(uu.y & 0xffffu)*invl_row; p.w = bf2f(uu.y >> 16)*invl_row;
            *(float4*)(probs + ((size_t)bh*S_LEN + q0 + trow)*S_LEN + kt*64 + c4*4) = p;
        }
        // PV MFMA on current Vs
        int prow = rt*16 + lh;
        bf16x8 pa[2];
        #pragma unroll
        for (int kk = 0; kk < 2; ++kk)
            pa[kk] = *(const bf16x8*)(Us + (size_t)kt*2048 + ((size_t)prow*8 + ((kk*4+g) ^ (prow & 7)))*8);
        #pragma unroll
        for (int kk = 0; kk < 2; ++kk) {
            int vr = dt1*16 + lh;
            bf16x8 vf = *(const bf16x8*)(Ks + ((size_t)vr*8 + ((kk*4+g) ^ (vr & 7)))*8);
            accA = MFMA16(pa[kk], vf, accA);
        }
        if (two) {
            #pragma unroll
            for (int kk = 0; kk < 2; ++kk) {
                int vr = dt2*16 + lh;
                bf16x8 vf = *(const bf16x8*)(Ks + ((size_t)vr*8 + ((kk*4+g) ^ (vr & 7)))*8);
                accB = MFMA16(pa[kk], vf, accB);
            }
        }
        __syncthreads();   // all Vs reads done
        if (kt < 31) {
            *(float4*)(Ks + ((size_t)vr_s*8 + (vc_s ^ (vr_s & 7)))*8) = vreg0;
            if (tid < 256)
                *(float4*)(Ks + ((size_t)vr2_s*8 + (vc2_s ^ (vr2_s & 7)))*8) = vreg1;
        }
        __syncthreads();   // Vs(kt+1) ready
    }

    // ctx write (scaled by invl per row)
    float ils[4];
    #pragma unroll
    for (int r = 0; r < 4; ++r) ils[r] = mL[rt*16 + g*4 + r];
    #pragma unroll
    for (int r = 0; r < 4; ++r) {
        int qrow = q0 + rt*16 + g*4 + r;
        ctxb[((size_t)(b*S_LEN + qrow))*EMB + h*HD + dt1*16 + lh] = f2bf(accA[r] * ils[r]);
        if (two)
            ctxb[((size_t)(b*S_LEN + qrow))*EMB + h*HD + dt2*16 + lh] = f2bf(accB[r] * ils[r]);
    }
}

// ---------------------------------------------------------------------------
// Output proj MFMA (unchanged)
// ---------------------------------------------------------------------------
__global__ __launch_bounds__(256) void out_mfma_kernel(
    const u16* __restrict__ ctxb, const u16* __restrict__ WoT,
    const float* __restrict__ bo, const float* __restrict__ hs,
    float* __restrict__ res)
{
    __shared__ __align__(16) u16 As[64*64];
    __shared__ __align__(16) u16 Bs[64*64];
    const int tid = threadIdx.x;
    const int w = tid >> 6, lane = tid & 63, lh = lane & 15, g = lane >> 4;
    const int wm = w >> 1, wn = w & 1;
    const int row0 = blockIdx.y * 64, col0 = blockIdx.x * 64;

    f32x4 acc[2][2];
    #pragma unroll
    for (int i = 0; i < 2; ++i)
        #pragma unroll
        for (int j = 0; j < 2; ++j) acc[i][j] = (f32x4){0.f,0.f,0.f,0.f};

    for (int k0 = 0; k0 < EMB; k0 += 64) {
        __syncthreads();
        #pragma unroll
        for (int i = 0; i < 2; ++i) {
            int idx = tid + 256*i;
            int r = idx >> 3, c = idx & 7;
            float4 a4 = *(const float4*)(ctxb + (size_t)(row0 + r)*EMB + k0 + c*8);
            *(float4*)(As + ((size_t)r*8 + (c ^ (r & 7)))*8) = a4;
            float4 b4 = *(const float4*)(WoT + (size_t)(col0 + r)*EMB + k0 + c*8);
            *(float4*)(Bs + ((size_t)r*8 + (c ^ (r & 7)))*8) = b4;
        }
        __syncthreads();
        bf16x8 af[2][2], bfr[2][2];
        #pragma unroll
        for (int mt = 0; mt < 2; ++mt)
            #pragma unroll
            for (int kk = 0; kk < 2; ++kk) {
                int r = wm*32 + mt*16 + lh;
                af[mt][kk] = *(const bf16x8*)(As + ((size_t)r*8 + ((kk*4+g) ^ (lh & 7)))*8);
            }
        #pragma unroll
        for (int nt = 0; nt < 2; ++nt)
            #pragma unroll
            for (int kk = 0; kk < 2; ++kk) {
                int r = wn*32 + nt*16 + lh;
                bfr[nt][kk] = *(const bf16x8*)(Bs + ((size_t)r*8 + ((kk*4+g) ^ (lh & 7)))*8);
            }
        #pragma unroll
        for (int mt = 0; mt < 2; ++mt)
            #pragma unroll
            for (int nt = 0; nt < 2; ++nt)
                #pragma unroll
                for (int kk = 0; kk < 2; ++kk)
                    acc[mt][nt] = MFMA16(af[mt][kk], bfr[nt][kk], acc[mt][nt]);
    }

    #pragma unroll
    for (int mt = 0; mt < 2; ++mt)
        #pragma unroll
        for (int nt = 0; nt < 2; ++nt)
            #pragma unroll
            for (int r = 0; r < 4; ++r) {
                int tt = row0 + wm*32 + mt*16 + g*4 + r;
                int o  = col0 + wn*32 + nt*16 + lh;
                res[(size_t)tt*EMB + o] = acc[mt][nt][r] + bo[o] + hs[(size_t)tt*EMB + o];
            }
}

// ---------------------------------------------------------------------------
// LayerNorm in place over last dim 768. grid NTOK, block 256.
// ---------------------------------------------------------------------------
__device__ __forceinline__ float block_sum256(float v, float* red) {
    #pragma unroll
    for (int off = 32; off > 0; off >>= 1) v += __shfl_down(v, off);
    int lane = threadIdx.x & 63, w = threadIdx.x >> 6;
    __syncthreads();
    if (lane == 0) red[w] = v;
    __syncthreads();
    return red[0] + red[1] + red[2] + red[3];
}

__global__ __launch_bounds__(256) void ln_kernel(
    float* __restrict__ res, const float* __restrict__ gamma, const float* __restrict__ beta)
{
    const int t = blockIdx.x;
    float* row = res + (size_t)t * EMB;
    const int tid = threadIdx.x;
    __shared__ float red[4];

    float x0 = row[tid], x1 = row[tid + 256], x2 = row[tid + 512];
    float s = block_sum256(x0 + x1 + x2, red);
    float mu = s * (1.0f / (float)EMB);
    float d0 = x0 - mu, d1 = x1 - mu, d2 = x2 - mu;
    float sq = block_sum256(d0*d0 + d1*d1 + d2*d2, red);
    float var = sq * (1.0f / (float)EMB);
    float scale = rsqrtf(var + 1e-5f);

    row[tid]       = d0 * scale * gamma[tid]       + beta[tid];
    row[tid + 256] = d1 * scale * gamma[tid + 256] + beta[tid + 256];
    row[tid + 512] = d2 * scale * gamma[tid + 512] + beta[tid + 512];
}

// ---------------------------------------------------------------------------
extern "C" void kernel_launch(void* const* d_in, const int* in_sizes, int n_in,
                              void* d_out, int out_size, void* d_ws, size_t ws_size,
                              hipStream_t stream)
{
    (void)in_sizes; (void)n_in; (void)out_size; (void)ws_size;

    const float* hs   = (const float*)d_in[0];
    const float* dist = (const float*)d_in[1];
    const float* ang  = (const float*)d_in[2];
    const float* mask = (const float*)d_in[3];
    const float* Wq = (const float*)d_in[4];  const float* bq = (const float*)d_in[5];
    const float* Wk = (const float*)d_in[6];  const float* bk = (const float*)d_in[7];
    const float* Wv = (const float*)d_in[8];  const float* bv = (const float*)d_in[9];
    const float* dw = (const float*)d_in[10]; const float* db = (const float*)d_in[11];
    const float* aw = (const float*)d_in[12]; const float* ab = (const float*)d_in[13];
    const float* Wo = (const float*)d_in[14]; const float* bo = (const float*)d_in[15];
    const float* gamma = (const float*)d_in[16]; const float* beta = (const float*)d_in[17];

    float* out   = (float*)d_out;                      // [B,S,E]
    float* probs = out + (size_t)NTOK * EMB;           // [B,H,S,S]

    u16* hsb = (u16*)d_ws;
    u16* WqT = hsb + (size_t)NTOK*EMB;
    u16* WkT = WqT + (size_t)EMB*EMB;
    u16* WvT = WkT + (size_t)EMB*EMB;
    u16* WoT = WvT + (size_t)EMB*EMB;
    u16* qb  = WoT + (size_t)EMB*EMB;
    u16* kb  = qb + (size_t)NTOK*EMB;
    u16* vb  = kb + (size_t)NTOK*EMB;
    u16* vtb = vb + (size_t)NTOK*EMB;
    u16* ctxb = qb;                                    // reuse q region after attn

    cvt_bf16_kernel<<<dim3(NTOK*EMB/4/256), dim3(256), 0, stream>>>(hs, hsb, NTOK*EMB/4);
    transcvt_kernel<<<dim3(12,12), dim3(256), 0, stream>>>(Wq, WqT);
    transcvt_kernel<<<dim3(12,12), dim3(256), 0, stream>>>(Wk, WkT);
    transcvt_kernel<<<dim3(12,12), dim3(256), 0, stream>>>(Wv, WvT);
    transcvt_kernel<<<dim3(12,12), dim3(256), 0, stream>>>(Wo, WoT);

    qkv_mfma_kernel<<<dim3(EMB/64, NTOK/64, 3), dim3(256), 0, stream>>>(
        hsb, WqT, bq, WkT, bk, WvT, bv, qb, kb, vb);

    vtrans_kernel<<<dim3(S_LEN/64, BATCH*NH), dim3(256), 0, stream>>>(vb, vtb);

    fused_attn_kernel<<<dim3(S_LEN/32, BATCH*NH), dim3(512), 0, stream>>>(
        qb, kb, vtb, dist, ang, mask, dw, db, aw, ab, probs, ctxb);

    out_mfma_kernel<<<dim3(EMB/64, NTOK/64), dim3(256), 0, stream>>>(
        ctxb, WoT, bo, hs, out);

    ln_kernel<<<dim3(NTOK), dim3(256), 0, stream>>>(out, gamma, beta);
}